// Round 11
// baseline (335.744 us; speedup 1.0000x reference)
//
#include <hip/hip_runtime.h>
#include <hip/hip_bf16.h>

typedef _Float16 f16;
typedef _Float16 half8 __attribute__((ext_vector_type(8)));
typedef _Float16 half4 __attribute__((ext_vector_type(4)));
typedef float f32x4 __attribute__((ext_vector_type(4)));

typedef const __attribute__((address_space(1))) void gvoid;
typedef __attribute__((address_space(3))) void lvoid;
#define GLOAD16(src, dst) __builtin_amdgcn_global_load_lds((gvoid*)(src), (lvoid*)(dst), 16, 0, 0)

// ---------------- workspace layout (bytes) ----------------
#define WQV_OFF   0u          // f32 [256][256]  Wq*Vp
#define WKT_OFF   262144u     // f32 [256][256]  Wk*Tp
#define KP_OFF    524288u     // f32 [512][256]  fused k-projection (l*16+b rows)
#define W2S_OFF   1048576u    // row-image W2s: [16 b][4 kc][256 j][128B] (swizzle baked)
#define SBIAS_OFF 3145728u    // f32 [16][256]
#define BQV_OFF   3162112u    // f32 [256]
#define BKT_OFF   3163136u    // f32 [256]
#define W1H_OFF   3164160u    // row-image W1: [4 kc][256 o][128B]
#define W2H_OFF   3295232u    // row-image W2: [4 kc][128 o][128B]
#define VARP_OFF  3360768u    // f32 [16][256]
#define SMM_OFF   3377280u    // u32 [16][2]
#define FMM_OFF   3377408u    // u32 [16][2]
#define CAND_OFF  3377664u    // f32 [9][16][16384]  plane-major candidates
#define FI_OFF    12814848u   // f32 [16][16384]
#define SIM_OFF   13863424u   // f32 [16][16384]
#define XS_OFF    14912000u   // f16 swizzled-image X: [16 b][16384 n][512 B] = 134 MB
#define XS_BYTES  134217728ull

__device__ __forceinline__ float sigm(float x) { return 1.f / (1.f + __expf(-x)); }
__device__ __forceinline__ unsigned fmap(float f) {
  unsigned u = __float_as_uint(f);
  return (u & 0x80000000u) ? ~u : (u | 0x80000000u);
}
__device__ __forceinline__ float funmap(unsigned u) {
  unsigned b = (u & 0x80000000u) ? (u & 0x7FFFFFFFu) : ~u;
  return __uint_as_float(b);
}

// ---------------- P1: Wqv = Wq*Vp, Wkt = Wk*Tp, fused biases (+minmax init) --------
__global__ void k_p1(const float* __restrict__ ipw, const float* __restrict__ ipb,
                     const float* __restrict__ vp_w, const float* __restrict__ vp_b,
                     const float* __restrict__ tp_w, const float* __restrict__ tp_b,
                     float* __restrict__ Wqv, float* __restrict__ Wkt,
                     float* __restrict__ bqv, float* __restrict__ bkt,
                     unsigned* __restrict__ simMM, unsigned* __restrict__ fiMM) {
  int tx = threadIdx.x, ty = threadIdx.y;
  int bz = blockIdx.z;
  if (bz == 2) {
    if (blockIdx.x || blockIdx.y) return;
    if (ty == 0 && tx < 16) {
      simMM[tx * 2] = 0xFFFFFFFFu; simMM[tx * 2 + 1] = 0u;
      fiMM[tx * 2] = 0xFFFFFFFFu;  fiMM[tx * 2 + 1] = 0u;
    }
    int j = ty * 16 + tx;
    float s1 = 0.f, s2 = 0.f;
    for (int k = 0; k < 256; ++k) {
      s1 += ipw[j * 256 + k] * vp_b[k];
      s2 += ipw[65536 + j * 256 + k] * tp_b[k];
    }
    bqv[j] = s1 + ipb[j];
    bkt[j] = s2 + ipb[256 + j];
    return;
  }
  const float* A = ipw + (bz ? 65536 : 0);
  const float* B = bz ? tp_w : vp_w;
  float* O = bz ? Wkt : Wqv;
  __shared__ float As[16][16], Bs[16][17];
  int row = blockIdx.y * 16 + ty, col = blockIdx.x * 16 + tx;
  float s = 0.f;
  for (int tt = 0; tt < 16; ++tt) {
    As[ty][tx] = A[row * 256 + tt * 16 + tx];
    Bs[ty][tx] = B[(tt * 16 + ty) * 256 + col];
    __syncthreads();
#pragma unroll
    for (int k = 0; k < 16; ++k) s += As[ty][k] * Bs[k][tx];
    __syncthreads();
  }
  O[row * 256 + col] = s;
}

// ---------------- convert W1/W2 to pre-swizzled row-image f16 ----------------
__global__ void k_conv(const float* __restrict__ w1, const float* __restrict__ w2,
                       char* __restrict__ W1g, char* __restrict__ W2g) {
  int i = blockIdx.x * 256 + threadIdx.x;
  if (i < 65536) {
    int o = i >> 8, c = i & 255;
    *(f16*)(W1g + (c >> 6) * 32768 + o * 128 + (((c & 63) << 1) ^ ((o & 7) << 4))) = (f16)w1[i];
  } else if (i < 98304) {
    int i2 = i - 65536;
    int o = i2 >> 8, c = i2 & 255;
    *(f16*)(W2g + (c >> 6) * 16384 + o * 128 + (((c & 63) << 1) ^ ((o & 7) << 4))) = (f16)w2[i2];
  }
}

// ---------------- k_tr: X [N,B,C] f32 -> XS [B][N][512B] f16 swizzled-image ----------
__global__ void __launch_bounds__(256) k_tr(const float* __restrict__ X,
                                            char* __restrict__ XS) {
  int g0 = blockIdx.x * 256 + threadIdx.x;
#pragma unroll 4
  for (int i = 0; i < 16; ++i) {
    int G = g0 + i * 524288;
    int cg = G & 31;          // granule within row (c = cg*8)
    int nb = G >> 5;          // n*16 + b
    int b = nb & 15;
    int n = nb >> 4;
    f32x4 a0 = *(const f32x4*)(X + (size_t)G * 8);
    f32x4 a1 = *(const f32x4*)(X + (size_t)G * 8 + 4);
    half8 h;
#pragma unroll
    for (int j = 0; j < 4; ++j) { h[j] = (f16)a0[j]; h[4 + j] = (f16)a1[j]; }
    unsigned off = (unsigned)((cg >> 3) * 128 + (((cg & 7) << 4) ^ ((n & 7) << 4)));
    *(half8*)(XS + ((size_t)b * 16384 + n) * 512 + off) = h;
  }
}

// ---------------- P2: kp[lb][i] = T[lb]·Wkt[i] + bkt[i] ----------------
__global__ void k_p2(const float* __restrict__ T, const float* __restrict__ Wkt,
                     const float* __restrict__ bkt, float* __restrict__ kp) {
  __shared__ float As[16][16], Ws[16][17];
  int tx = threadIdx.x, ty = threadIdx.y;
  int lb = blockIdx.y * 16 + ty;
  int i = blockIdx.x * 16 + tx;
  float s = 0.f;
  for (int tt = 0; tt < 16; ++tt) {
    As[ty][tx] = T[(size_t)lb * 256 + tt * 16 + tx];
    Ws[ty][tx] = Wkt[(size_t)(blockIdx.x * 16 + ty) * 256 + tt * 16 + tx];
    __syncthreads();
#pragma unroll
    for (int k = 0; k < 16; ++k) s += As[ty][k] * Ws[tx][k];
    __syncthreads();
  }
  kp[(size_t)lb * 256 + i] = s + bkt[i];
}

// ---------------- P3: W2s (pre-swizzled row-image) + sbias ----------------
__global__ void k_p3(const float* __restrict__ kp, const float* __restrict__ Wqv,
                     const float* __restrict__ bqv, char* __restrict__ W2sg,
                     float* __restrict__ sbias) {
  const float SC = 0.17677669529663687f; // 1/sqrt(32)
  int b = blockIdx.z, jt = blockIdx.y, ct = blockIdx.x;
  int ty = threadIdx.y, tx = threadIdx.x;
  int j2 = jt * 16 + ty, c = ct * 16 + tx;
  int h = j2 >> 5, l = j2 & 31;
  const float* kr = kp + (size_t)(l * 16 + b) * 256 + h * 32;
  const float* wq = Wqv + (size_t)h * 32 * 256 + c;
  float s = 0.f;
#pragma unroll
  for (int d = 0; d < 32; ++d) s += kr[d] * wq[(size_t)d * 256];
  *(f16*)(W2sg + (size_t)b * 131072 + (c >> 6) * 32768 + j2 * 128 +
          (((c & 63) << 1) ^ ((j2 & 7) << 4))) = (f16)(s * SC);
  if (ct == 0 && tx == 0) {
    float sb = 0.f;
#pragma unroll
    for (int d = 0; d < 32; ++d) sb += kr[d] * bqv[h * 32 + d];
    sbias[b * 256 + j2] = sb * SC;
  }
}

// ============ k_sc: scores GEMM (2-phase pipelined dbuf) + softmax + top16 ============
// LDS (81920 = 2 blocks/CU): AT0@0 8K, AT1@8K, BT0@16K 32K, BT1@48K 32K.
// slices (post-GEMM) alias BT0: 4 waves x 8K @16K.
template <int CONT>
__global__ void __launch_bounds__(256, 2) k_sc(
    const float* __restrict__ X, const char* __restrict__ XSg,
    const char* __restrict__ W2sg, const float* __restrict__ sbias,
    float* __restrict__ cand, float* __restrict__ varpart) {
  __shared__ __align__(16) char smem[81920];
  const int b = blockIdx.y;
  const int bx = blockIdx.x;
  const int n0 = bx * 64;
  const int t = threadIdx.x;
  const int w = t >> 6;
  const int lane = t & 63;
  const int ln = lane & 15, kg = lane >> 4;
  const char* XSb = XSg + ((size_t)b * 16384 + n0) * 512;
  const char* Wb = W2sg + (size_t)b * 131072;

  auto issueA = [&](int kt, int p) {
    char* ATp = smem + p * 8192;
    if constexpr (CONT) {
      const char* src = XSb + (size_t)(w * 16 + (lane >> 3)) * 512 + kt * 128 + ((lane & 7) << 4);
      GLOAD16(src, ATp + w * 2048);
      GLOAD16(src + 8 * 512, ATp + w * 2048 + 1024);
    } else {
      int row = t >> 2, cq = t & 3;
      const float* Xr = X + ((size_t)(n0 + row) * 16 + b) * 256 + kt * 64 + cq * 16;
      f32x4 a0 = *(const f32x4*)(Xr), a1 = *(const f32x4*)(Xr + 4);
      f32x4 a2 = *(const f32x4*)(Xr + 8), a3 = *(const f32x4*)(Xr + 12);
      half8 h0, h1;
#pragma unroll
      for (int i = 0; i < 4; ++i) {
        h0[i] = (f16)a0[i]; h0[4 + i] = (f16)a1[i];
        h1[i] = (f16)a2[i]; h1[4 + i] = (f16)a3[i];
      }
      unsigned sw = (unsigned)((row & 7) << 4);
      *(half8*)(ATp + ((unsigned)(row * 128 + cq * 32) ^ sw)) = h0;
      *(half8*)(ATp + ((unsigned)(row * 128 + cq * 32 + 16) ^ sw)) = h1;
    }
  };
  auto issueB = [&](int kt, int p) {
    const char* src = Wb + kt * 32768 + w * 8192 + (lane << 4);
    char* dst = smem + 16384 + p * 32768 + w * 8192;
#pragma unroll
    for (int i = 0; i < 8; ++i) GLOAD16(src + i * 1024, dst + i * 1024);
  };

  f32x4 acc[4][4];
#pragma unroll
  for (int q = 0; q < 4; ++q)
#pragma unroll
    for (int ni = 0; ni < 4; ++ni)
#pragma unroll
      for (int i = 0; i < 4; ++i) acc[q][ni][i] = 0.f;

  issueA(0, 0); issueB(0, 0);
  __syncthreads();
#pragma unroll
  for (int kt = 0; kt < 4; ++kt) {
    const int p = kt & 1;
    if (kt < 3) { issueA(kt + 1, p ^ 1); issueB(kt + 1, p ^ 1); }  // DMA overlaps MFMA
    char* ATp = smem + p * 8192;
    char* BTp = smem + 16384 + p * 32768;
    half8 av[4][2], bv[4][2];
#pragma unroll
    for (int q = 0; q < 4; ++q) {
      int o = w * 64 + q * 16 + ln;
      unsigned sw = (unsigned)((o & 7) << 4);
#pragma unroll
      for (int mi = 0; mi < 2; ++mi)
        av[q][mi] = *(const half8*)(BTp + o * 128 + ((unsigned)(mi * 64 + kg * 16) ^ sw));
    }
#pragma unroll
    for (int ni = 0; ni < 4; ++ni) {
      int n = ni * 16 + ln;
      unsigned sw = (unsigned)((n & 7) << 4);
#pragma unroll
      for (int mi = 0; mi < 2; ++mi)
        bv[ni][mi] = *(const half8*)(ATp + n * 128 + ((unsigned)(mi * 64 + kg * 16) ^ sw));
    }
#pragma unroll
    for (int mi = 0; mi < 2; ++mi)
#pragma unroll
      for (int q = 0; q < 4; ++q)
#pragma unroll
        for (int ni = 0; ni < 4; ++ni)
          acc[q][ni] = __builtin_amdgcn_mfma_f32_16x16x32_f16(av[q][mi], bv[ni][mi], acc[q][ni], 0, 0, 0);
    __syncthreads();  // next tile landed; this tile's reads done
  }

  // ---- per-head softmax (wave w: heads 2w, 2w+1), slice into dead BT0 ----
  {
    f32x4 sb[4];
#pragma unroll
    for (int q = 0; q < 4; ++q)
      sb[q] = *(const f32x4*)(sbias + b * 256 + (w * 4 + q) * 16 + kg * 4);
    float vm[4][2][4];
#pragma unroll
    for (int ni = 0; ni < 4; ++ni)
#pragma unroll
      for (int qq = 0; qq < 2; ++qq)
#pragma unroll
        for (int r = 0; r < 4; ++r) vm[ni][qq][r] = 0.f;
#pragma unroll
    for (int hh = 0; hh < 2; ++hh)
#pragma unroll
      for (int ni = 0; ni < 4; ++ni) {
        float x[2][4];
        float mx = -1e30f;
#pragma unroll
        for (int qq = 0; qq < 2; ++qq)
#pragma unroll
          for (int r = 0; r < 4; ++r) {
            x[qq][r] = acc[hh * 2 + qq][ni][r] + sb[hh * 2 + qq][r];
            mx = fmaxf(mx, x[qq][r]);
          }
        mx = fmaxf(mx, __shfl_xor(mx, 16, 64));
        mx = fmaxf(mx, __shfl_xor(mx, 32, 64));
        float S = 0.f;
#pragma unroll
        for (int qq = 0; qq < 2; ++qq)
#pragma unroll
          for (int r = 0; r < 4; ++r) { x[qq][r] = __expf(x[qq][r] - mx); S += x[qq][r]; }
        S += __shfl_xor(S, 16, 64);
        S += __shfl_xor(S, 32, 64);
        float inv = 0.125f / S;
#pragma unroll
        for (int qq = 0; qq < 2; ++qq)
#pragma unroll
          for (int r = 0; r < 4; ++r) vm[ni][qq][r] += x[qq][r] * inv;
      }
    float* slice = (float*)(smem + 16384) + w * 2048;  // [32 l][64 n]
#pragma unroll
    for (int ni = 0; ni < 4; ++ni)
#pragma unroll
      for (int qq = 0; qq < 2; ++qq)
#pragma unroll
        for (int r = 0; r < 4; ++r)
          slice[(qq * 16 + kg * 4 + r) * 64 + ni * 16 + ln] = vm[ni][qq][r];
  }
  __syncthreads();

  // ---- wave 0: merge slices, variance, sort, candidates ----
  if (w == 0) {
    const float* sl = (const float*)(smem + 16384);
    float v[32];
#pragma unroll
    for (int l = 0; l < 32; ++l)
      v[l] = sl[l * 64 + lane] + sl[2048 + l * 64 + lane] +
             sl[4096 + l * 64 + lane] + sl[6144 + l * 64 + lane];
    float s2 = 0.f;
#pragma unroll
    for (int l = 0; l < 32; ++l) s2 += v[l] * v[l];
    float vr = (s2 - (1.f / 32.f)) * (1.f / 31.f);
#pragma unroll
    for (int m = 1; m < 64; m <<= 1) vr += __shfl_xor(vr, m, 64);
    if (lane == 0) varpart[b * 256 + bx] = vr;
#pragma unroll
    for (int k = 2; k <= 32; k <<= 1) {
#pragma unroll
      for (int j = k >> 1; j > 0; j >>= 1) {
#pragma unroll
        for (int i = 0; i < 32; ++i) {
          int l = i ^ j;
          if (l > i) {
            float a = v[i], c = v[l];
            float hi = fmaxf(a, c), lo = fminf(a, c);
            bool up = ((i & k) == 0);
            v[i] = up ? hi : lo;
            v[l] = up ? lo : hi;
          }
        }
      }
    }
    float m0 = v[0], se = 0.f, te = 0.f;
    float cn[9];
#pragma unroll
    for (int i = 0; i < 16; ++i) {
      float e = __expf(v[i] - m0);
      se += e; te += v[i] * e;
      if (i >= 7) cn[i - 7] = te / se;
    }
#pragma unroll
    for (int i = 0; i < 9; ++i)
      cand[(size_t)i * 262144 + (size_t)b * 16384 + n0 + lane] = cn[i];
  }
}

// ============ k_mlp: MLP1 (pipelined) + LN1 + MLP2 (pipelined) + LN2 + w3·sigmoid ============
// LDS (81920 = 2/CU) phase1: AT0@0 8K, AT1@8K, BT0@16K 32K, BT1@48K 32K.
// phase2: H1@0 32K, W2T0@32K 16K, W2T1@48K 16K. stats carved @64K.
template <int CONT>
__global__ void __launch_bounds__(256, 2) k_mlp(
    const float* __restrict__ X, const char* __restrict__ XSg,
    const char* __restrict__ W1g, const char* __restrict__ W2g,
    const float* __restrict__ b1, const float* __restrict__ g1, const float* __restrict__ be1,
    const float* __restrict__ b2, const float* __restrict__ g2, const float* __restrict__ be2,
    const float* __restrict__ w3, const float* __restrict__ b3,
    float* __restrict__ fi) {
  __shared__ __align__(16) char smem[81920];
  float* pS = (float*)(smem + 65536);        // [64][5]
  float* pQ = (float*)(smem + 66816);        // [64][5]
  float* pM = (float*)(smem + 68096);        // [64]
  float* pR = (float*)(smem + 68352);        // [64]
  const int b = blockIdx.y;
  const int bx = blockIdx.x;
  const int n0 = bx * 64;
  const int t = threadIdx.x;
  const int w = t >> 6;
  const int lane = t & 63;
  const int ln = lane & 15, kg = lane >> 4;
  char* H1 = smem;
  const char* XSb = XSg + ((size_t)b * 16384 + n0) * 512;

  auto issueA = [&](int kt, int p) {
    char* ATp = smem + p * 8192;
    if constexpr (CONT) {
      const char* src = XSb + (size_t)(w * 16 + (lane >> 3)) * 512 + kt * 128 + ((lane & 7) << 4);
      GLOAD16(src, ATp + w * 2048);
      GLOAD16(src + 8 * 512, ATp + w * 2048 + 1024);
    } else {
      int row = t >> 2, cq = t & 3;
      const float* Xr = X + ((size_t)(n0 + row) * 16 + b) * 256 + kt * 64 + cq * 16;
      f32x4 a0 = *(const f32x4*)(Xr), a1 = *(const f32x4*)(Xr + 4);
      f32x4 a2 = *(const f32x4*)(Xr + 8), a3 = *(const f32x4*)(Xr + 12);
      half8 h0, h1;
#pragma unroll
      for (int i = 0; i < 4; ++i) {
        h0[i] = (f16)a0[i]; h0[4 + i] = (f16)a1[i];
        h1[i] = (f16)a2[i]; h1[4 + i] = (f16)a3[i];
      }
      unsigned sw = (unsigned)((row & 7) << 4);
      *(half8*)(ATp + ((unsigned)(row * 128 + cq * 32) ^ sw)) = h0;
      *(half8*)(ATp + ((unsigned)(row * 128 + cq * 32 + 16) ^ sw)) = h1;
    }
  };
  auto issueB1 = [&](int kt, int p) {
    const char* src = W1g + kt * 32768 + w * 8192 + (lane << 4);
    char* dst = smem + 16384 + p * 32768 + w * 8192;
#pragma unroll
    for (int i = 0; i < 8; ++i) GLOAD16(src + i * 1024, dst + i * 1024);
  };
  auto issueW2 = [&](int kt, int p) {
    const char* src = W2g + kt * 16384 + w * 4096 + (lane << 4);
    char* dst = smem + 32768 + p * 16384 + w * 4096;
    GLOAD16(src, dst);
    GLOAD16(src + 1024, dst + 1024);
    GLOAD16(src + 2048, dst + 2048);
    GLOAD16(src + 3072, dst + 3072);
  };

  // ================= MLP1 GEMM (pipelined) =================
  f32x4 acc[4][4];
#pragma unroll
  for (int q = 0; q < 4; ++q)
#pragma unroll
    for (int ni = 0; ni < 4; ++ni)
#pragma unroll
      for (int i = 0; i < 4; ++i) acc[q][ni][i] = 0.f;

  issueA(0, 0); issueB1(0, 0);
  __syncthreads();
#pragma unroll
  for (int kt = 0; kt < 4; ++kt) {
    const int p = kt & 1;
    if (kt < 3) { issueA(kt + 1, p ^ 1); issueB1(kt + 1, p ^ 1); }
    char* ATp = smem + p * 8192;
    char* BTp = smem + 16384 + p * 32768;
    half8 av[4][2], bv[4][2];
#pragma unroll
    for (int q = 0; q < 4; ++q) {
      int o = w * 64 + q * 16 + ln;
      unsigned sw = (unsigned)((o & 7) << 4);
#pragma unroll
      for (int mi = 0; mi < 2; ++mi)
        av[q][mi] = *(const half8*)(BTp + o * 128 + ((unsigned)(mi * 64 + kg * 16) ^ sw));
    }
#pragma unroll
    for (int ni = 0; ni < 4; ++ni) {
      int n = ni * 16 + ln;
      unsigned sw = (unsigned)((n & 7) << 4);
#pragma unroll
      for (int mi = 0; mi < 2; ++mi)
        bv[ni][mi] = *(const half8*)(ATp + n * 128 + ((unsigned)(mi * 64 + kg * 16) ^ sw));
    }
#pragma unroll
    for (int mi = 0; mi < 2; ++mi)
#pragma unroll
      for (int q = 0; q < 4; ++q)
#pragma unroll
        for (int ni = 0; ni < 4; ++ni)
          acc[q][ni] = __builtin_amdgcn_mfma_f32_16x16x32_f16(av[q][mi], bv[ni][mi], acc[q][ni], 0, 0, 0);
    __syncthreads();
  }

  // ---- b1 + LN1 partials (buffers dead; stats region independent @64K+) ----
  {
    f32x4 b1v[4];
#pragma unroll
    for (int q = 0; q < 4; ++q)
      b1v[q] = *(const f32x4*)(b1 + (w * 4 + q) * 16 + kg * 4);
#pragma unroll
    for (int ni = 0; ni < 4; ++ni) {
      float s = 0.f, qq = 0.f;
#pragma unroll
      for (int q = 0; q < 4; ++q)
#pragma unroll
        for (int r = 0; r < 4; ++r) {
          float v = acc[q][ni][r] + b1v[q][r];
          acc[q][ni][r] = v;
          s += v; qq += v * v;
        }
      s += __shfl_xor(s, 16, 64); s += __shfl_xor(s, 32, 64);
      qq += __shfl_xor(qq, 16, 64); qq += __shfl_xor(qq, 32, 64);
      if (kg == 0) { int n = ni * 16 + ln; pS[n * 5 + w] = s; pQ[n * 5 + w] = qq; }
    }
  }
  __syncthreads();
  if (t < 64) {
    float s = pS[t * 5 + 0] + pS[t * 5 + 1] + pS[t * 5 + 2] + pS[t * 5 + 3];
    float q = pQ[t * 5 + 0] + pQ[t * 5 + 1] + pQ[t * 5 + 2] + pQ[t * 5 + 3];
    float mean = s * (1.f / 256.f);
    float var = q * (1.f / 256.f) - mean * mean;
    pM[t] = mean;
    pR[t] = rsqrtf(var + 1e-5f);
  }
  __syncthreads();

  // ---- LN1 apply + ReLU -> H1 @0 ; W2 chunk0 DMA overlaps this epilogue ----
  issueW2(0, 0);
  {
    f32x4 g1v[4], e1v[4];
#pragma unroll
    for (int q = 0; q < 4; ++q) {
      g1v[q] = *(const f32x4*)(g1 + (w * 4 + q) * 16 + kg * 4);
      e1v[q] = *(const f32x4*)(be1 + (w * 4 + q) * 16 + kg * 4);
    }
#pragma unroll
    for (int ni = 0; ni < 4; ++ni) {
      int n = ni * 16 + ln;
      float mean = pM[n], rstd = pR[n];
      unsigned sw = (unsigned)((n & 7) << 4);
#pragma unroll
      for (int q = 0; q < 4; ++q) {
        half4 hv;
#pragma unroll
        for (int r = 0; r < 4; ++r) {
          float y = (acc[q][ni][r] - mean) * rstd * g1v[q][r] + e1v[q][r];
          hv[r] = (f16)fmaxf(y, 0.f);
        }
        *(half4*)(H1 + ((unsigned)(n * 512 + (w * 4 + q) * 32 + kg * 8) ^ sw)) = hv;
      }
    }
  }
  __syncthreads();  // H1 visible + W2T(0) landed

  // ================= MLP2 [128 o2]x[64 n], K=256 (pipelined) =================
  f32x4 acc2[2][4];
#pragma unroll
  for (int oi = 0; oi < 2; ++oi)
#pragma unroll
    for (int ni = 0; ni < 4; ++ni)
#pragma unroll
      for (int i = 0; i < 4; ++i) acc2[oi][ni][i] = 0.f;
#pragma unroll
  for (int kt = 0; kt < 4; ++kt) {
    const int p = kt & 1;
    if (kt < 3) issueW2(kt + 1, p ^ 1);
    char* W2Tp = smem + 32768 + p * 16384;
    half8 a2[2][2], bv[4][2];
#pragma unroll
    for (int oi = 0; oi < 2; ++oi) {
      int o2 = w * 32 + oi * 16 + ln;
      unsigned sw = (unsigned)((o2 & 7) << 4);
#pragma unroll
      for (int mi = 0; mi < 2; ++mi)
        a2[oi][mi] = *(const half8*)(W2Tp + o2 * 128 + ((unsigned)(mi * 64 + kg * 16) ^ sw));
    }
#pragma unroll
    for (int ni = 0; ni < 4; ++ni) {
      int n = ni * 16 + ln;
      unsigned sw = (unsigned)((n & 7) << 4);
#pragma unroll
      for (int mi = 0; mi < 2; ++mi)
        bv[ni][mi] = *(const half8*)(H1 + n * 512 + kt * 128 + ((unsigned)(mi * 64 + kg * 16) ^ sw));
    }
#pragma unroll
    for (int mi = 0; mi < 2; ++mi)
#pragma unroll
      for (int oi = 0; oi < 2; ++oi)
#pragma unroll
        for (int ni = 0; ni < 4; ++ni)
          acc2[oi][ni] = __builtin_amdgcn_mfma_f32_16x16x32_f16(a2[oi][mi], bv[ni][mi], acc2[oi][ni], 0, 0, 0);
    __syncthreads();
  }

  // ---- LN2 + ReLU + w3 dot + sigmoid -> fi ----
  {
    f32x4 b2v[2], g2v[2], e2v[2], w3v[2];
#pragma unroll
    for (int oi = 0; oi < 2; ++oi) {
      b2v[oi] = *(const f32x4*)(b2 + (w * 2 + oi) * 16 + kg * 4);
      g2v[oi] = *(const f32x4*)(g2 + (w * 2 + oi) * 16 + kg * 4);
      e2v[oi] = *(const f32x4*)(be2 + (w * 2 + oi) * 16 + kg * 4);
      w3v[oi] = *(const f32x4*)(w3 + (w * 2 + oi) * 16 + kg * 4);
    }
#pragma unroll
    for (int ni = 0; ni < 4; ++ni) {
      float s = 0.f, q = 0.f;
#pragma unroll
      for (int oi = 0; oi < 2; ++oi)
#pragma unroll
        for (int r = 0; r < 4; ++r) {
          float v = acc2[oi][ni][r] + b2v[oi][r];
          acc2[oi][ni][r] = v;
          s += v; q += v * v;
        }
      s += __shfl_xor(s, 16, 64); s += __shfl_xor(s, 32, 64);
      q += __shfl_xor(q, 16, 64); q += __shfl_xor(q, 32, 64);
      if (kg == 0) { int n = ni * 16 + ln; pS[n * 5 + w] = s; pQ[n * 5 + w] = q; }
    }
    __syncthreads();
    if (t < 64) {
      float s = pS[t * 5 + 0] + pS[t * 5 + 1] + pS[t * 5 + 2] + pS[t * 5 + 3];
      float q = pQ[t * 5 + 0] + pQ[t * 5 + 1] + pQ[t * 5 + 2] + pQ[t * 5 + 3];
      float mean = s * (1.f / 128.f);
      float var = q * (1.f / 128.f) - mean * mean;
      pM[t] = mean;
      pR[t] = rsqrtf(var + 1e-5f);
    }
    __syncthreads();
#pragma unroll
    for (int ni = 0; ni < 4; ++ni) {
      int n = ni * 16 + ln;
      float mean = pM[n], rstd = pR[n];
      float a3 = 0.f;
#pragma unroll
      for (int oi = 0; oi < 2; ++oi)
#pragma unroll
        for (int r = 0; r < 4; ++r) {
          float y = (acc2[oi][ni][r] - mean) * rstd * g2v[oi][r] + e2v[oi][r];
          a3 += fmaxf(y, 0.f) * w3v[oi][r];
        }
      a3 += __shfl_xor(a3, 16, 64);
      a3 += __shfl_xor(a3, 32, 64);
      if (kg == 0) pS[n * 5 + w] = a3;
    }
    __syncthreads();
    if (t < 64) {
      float z = pS[t * 5 + 0] + pS[t * 5 + 1] + pS[t * 5 + 2] + pS[t * 5 + 3] + b3[0];
      fi[(size_t)b * 16384 + n0 + t] = sigm(z);
    }
  }
}

// ---------------- G4: ktop + pick sim candidate + min/max reductions ----------------
__global__ void __launch_bounds__(256) k_g4(
    const float* __restrict__ cand, const float* __restrict__ fi,
    const float* __restrict__ varpart, const float* __restrict__ kw,
    float* __restrict__ sim, unsigned* __restrict__ simMM, unsigned* __restrict__ fiMM) {
  __shared__ float red[4][4];
  __shared__ int kS;
  int b = blockIdx.x >> 6;
  if (threadIdx.x < 64) {
    float s = 0.f;
#pragma unroll
    for (int i = 0; i < 4; ++i) s += varpart[b * 256 + threadIdx.x + i * 64];
#pragma unroll
    for (int m = 1; m < 64; m <<= 1) s += __shfl_xor(s, m, 64);
    if (threadIdx.x == 0) {
      float var = s * (1.f / 16384.f);
      float kws = sigm(kw[0]);
      float ratio = fminf(fmaxf(kws * (1.f + var * 0.5f), 0.25f), 0.6f);
      int kb = (int)floorf(32.f * ratio);
      if (kb < 1) kb = 1;
      int kt = kb < 16 ? kb : 16;
      if (kt < 8) kt = 8;
      kS = kt;
    }
  }
  __syncthreads();
  int k = kS;
  int n = (blockIdx.x & 63) * 256 + threadIdx.x;
  size_t idx = (size_t)b * 16384 + n;
  float sv = cand[(size_t)(k - 8) * 262144 + idx];
  sim[idx] = sv;
  float fv = fi[idx];
  float sn = sv, sx = sv, fn = fv, fx = fv;
#pragma unroll
  for (int m = 1; m < 64; m <<= 1) {
    sn = fminf(sn, __shfl_xor(sn, m, 64));
    sx = fmaxf(sx, __shfl_xor(sx, m, 64));
    fn = fminf(fn, __shfl_xor(fn, m, 64));
    fx = fmaxf(fx, __shfl_xor(fx, m, 64));
  }
  int wv = threadIdx.x >> 6;
  if ((threadIdx.x & 63) == 0) { red[0][wv] = sn; red[1][wv] = sx; red[2][wv] = fn; red[3][wv] = fx; }
  __syncthreads();
  if (threadIdx.x == 0) {
    float a = red[0][0], c = red[1][0], d = red[2][0], e = red[3][0];
#pragma unroll
    for (int i = 1; i < 4; ++i) {
      a = fminf(a, red[0][i]); c = fmaxf(c, red[1][i]);
      d = fminf(d, red[2][i]); e = fmaxf(e, red[3][i]);
    }
    atomicMin(&simMM[b * 2 + 0], fmap(a));
    atomicMax(&simMM[b * 2 + 1], fmap(c));
    atomicMin(&fiMM[b * 2 + 0], fmap(d));
    atomicMax(&fiMM[b * 2 + 1], fmap(e));
  }
}

// ---------------- G5: normalize, combine, transpose-write ----------------
__global__ void __launch_bounds__(256) k_g5(
    const float* __restrict__ sim, const float* __restrict__ fi,
    const unsigned* __restrict__ simMM, const unsigned* __restrict__ fiMM,
    const float* __restrict__ ac, const float* __restrict__ af,
    float* __restrict__ out) {
  __shared__ float ls[256][17], lf[256][17];
  __shared__ float sMin[16], sInv[16], fMin[16], fInv[16];
  int t = threadIdx.x;
  int n0 = blockIdx.x * 256;
  if (t < 16) {
    float lo = funmap(simMM[t * 2]), hi = funmap(simMM[t * 2 + 1]);
    float r = hi - lo;
    sMin[t] = lo; sInv[t] = (r > 0.f) ? 1.f / r : 0.f;
    lo = funmap(fiMM[t * 2]); hi = funmap(fiMM[t * 2 + 1]);
    r = hi - lo;
    fMin[t] = lo; fInv[t] = (r > 0.f) ? 1.f / r : 0.f;
  }
#pragma unroll
  for (int i = 0; i < 16; ++i) {
    ls[t][i] = sim[(size_t)i * 16384 + n0 + t];
    lf[t][i] = fi[(size_t)i * 16384 + n0 + t];
  }
  __syncthreads();
  float alpha = 0.5f * (sigm(ac[0]) + sigm(af[0]));
  float o[16];
#pragma unroll
  for (int b = 0; b < 16; ++b) {
    float s = (ls[t][b] - sMin[b]) * sInv[b];
    float f = (lf[t][b] - fMin[b]) * fInv[b];
    o[b] = alpha * s + (1.f - alpha) * f;
  }
  float* op = out + (size_t)(n0 + t) * 16;
#pragma unroll
  for (int i = 0; i < 4; ++i) {
    f32x4 v;
    v[0] = o[i * 4]; v[1] = o[i * 4 + 1]; v[2] = o[i * 4 + 2]; v[3] = o[i * 4 + 3];
    *(f32x4*)(op + i * 4) = v;
  }
}

// ---------------- launcher ----------------
extern "C" void kernel_launch(void* const* d_in, const int* in_sizes, int n_in,
                              void* d_out, int out_size, void* d_ws, size_t ws_size,
                              hipStream_t stream) {
  const float* X    = (const float*)d_in[0];
  const float* T    = (const float*)d_in[1];
  const float* vp_w = (const float*)d_in[2];
  const float* vp_b = (const float*)d_in[3];
  const float* tp_w = (const float*)d_in[4];
  const float* tp_b = (const float*)d_in[5];
  const float* ipw  = (const float*)d_in[6];
  const float* ipb  = (const float*)d_in[7];
  const float* w1   = (const float*)d_in[8];
  const float* b1   = (const float*)d_in[9];
  const float* g1   = (const float*)d_in[10];
  const float* be1  = (const float*)d_in[11];
  const float* w2   = (const float*)d_in[12];
  const float* b2   = (const float*)d_in[13];
  const float* g2   = (const float*)d_in[14];
  const float* be2  = (const float*)d_in[15];
  const float* w3   = (const float*)d_in[16];
  const float* b3   = (const float*)d_in[17];
  const float* kw   = (const float*)d_in[18];
  const float* ac   = (const float*)d_in[19];
  const float* af   = (const float*)d_in[20];
  char* ws = (char*)d_ws;
  float* Wqv = (float*)(ws + WQV_OFF);
  float* Wkt = (float*)(ws + WKT_OFF);
  float* kp = (float*)(ws + KP_OFF);
  char* W2sg = ws + W2S_OFF;
  float* sbias = (float*)(ws + SBIAS_OFF);
  float* bqv = (float*)(ws + BQV_OFF);
  float* bkt = (float*)(ws + BKT_OFF);
  char* W1g = ws + W1H_OFF;
  char* W2g = ws + W2H_OFF;
  float* varpart = (float*)(ws + VARP_OFF);
  unsigned* simMM = (unsigned*)(ws + SMM_OFF);
  unsigned* fiMM = (unsigned*)(ws + FMM_OFF);
  float* cand = (float*)(ws + CAND_OFF);
  float* fi = (float*)(ws + FI_OFF);
  float* sim = (float*)(ws + SIM_OFF);
  char* XS = ws + XS_OFF;
  float* out = (float*)d_out;

  const bool cont = (ws_size >= (size_t)XS_OFF + XS_BYTES);

  k_p1<<<dim3(16, 16, 3), dim3(16, 16), 0, stream>>>(ipw, ipb, vp_w, vp_b, tp_w, tp_b,
                                                     Wqv, Wkt, bqv, bkt, simMM, fiMM);
  k_conv<<<384, 256, 0, stream>>>(w1, w2, W1g, W2g);
  if (cont) k_tr<<<2048, 256, 0, stream>>>(X, XS);
  k_p2<<<dim3(16, 32), dim3(16, 16), 0, stream>>>(T, Wkt, bkt, kp);
  k_p3<<<dim3(16, 16, 16), dim3(16, 16), 0, stream>>>(kp, Wqv, bqv, W2sg, sbias);
  if (cont) {
    k_sc<1><<<dim3(256, 16), 256, 0, stream>>>(X, XS, W2sg, sbias, cand, varpart);
    k_mlp<1><<<dim3(256, 16), 256, 0, stream>>>(X, XS, W1g, W2g, b1, g1, be1,
                                                b2, g2, be2, w3, b3, fi);
  } else {
    k_sc<0><<<dim3(256, 16), 256, 0, stream>>>(X, XS, W2sg, sbias, cand, varpart);
    k_mlp<0><<<dim3(256, 16), 256, 0, stream>>>(X, XS, W1g, W2g, b1, g1, be1,
                                                b2, g2, be2, w3, b3, fi);
  }
  k_g4<<<1024, 256, 0, stream>>>(cand, fi, varpart, kw, sim, simMM, fiMM);
  k_g5<<<64, 256, 0, stream>>>(sim, fi, simMM, fiMM, ac, af, out);
}

// Round 12
// 270.961 us; speedup vs baseline: 1.2391x; 1.2391x over previous
//
#include <hip/hip_runtime.h>
#include <hip/hip_bf16.h>

typedef _Float16 f16;
typedef _Float16 half8 __attribute__((ext_vector_type(8)));
typedef _Float16 half4 __attribute__((ext_vector_type(4)));
typedef float f32x4 __attribute__((ext_vector_type(4)));

typedef const __attribute__((address_space(1))) void gvoid;
typedef __attribute__((address_space(3))) void lvoid;
#define GLOAD16(src, dst) __builtin_amdgcn_global_load_lds((gvoid*)(src), (lvoid*)(dst), 16, 0, 0)

// ---------------- workspace layout (bytes) ----------------
#define WQV_OFF   0u          // f32 [256][256]  Wq*Vp
#define WKT_OFF   262144u     // f32 [256][256]  Wk*Tp
#define KP_OFF    524288u     // f32 [512][256]  fused k-projection (l*16+b rows)
#define W2S_OFF   1048576u    // row-image W2s: [16 b][4 kc][256 j][128B] (swizzle baked)
#define SBIAS_OFF 3145728u    // f32 [16][256]
#define BQV_OFF   3162112u    // f32 [256]
#define BKT_OFF   3163136u    // f32 [256]
#define W1H_OFF   3164160u    // row-image W1: [4 kc][256 o][128B]
#define W2H_OFF   3295232u    // row-image W2: [4 kc][128 o][128B]
#define VARP_OFF  3360768u    // f32 [16][256]
#define SMM_OFF   3377280u    // u32 [16][2]
#define FMM_OFF   3377408u    // u32 [16][2]
#define CAND_OFF  3377664u    // f32 [9][16][16384]  plane-major candidates
#define FI_OFF    12814848u   // f32 [16][16384]
#define SIM_OFF   13863424u   // f32 [16][16384]

__device__ __forceinline__ float sigm(float x) { return 1.f / (1.f + __expf(-x)); }
__device__ __forceinline__ unsigned fmap(float f) {
  unsigned u = __float_as_uint(f);
  return (u & 0x80000000u) ? ~u : (u | 0x80000000u);
}
__device__ __forceinline__ float funmap(unsigned u) {
  unsigned b = (u & 0x80000000u) ? (u & 0x7FFFFFFFu) : ~u;
  return __uint_as_float(b);
}

// ---------------- P1: Wqv = Wq*Vp, Wkt = Wk*Tp, fused biases (+minmax init) --------
__global__ void k_p1(const float* __restrict__ ipw, const float* __restrict__ ipb,
                     const float* __restrict__ vp_w, const float* __restrict__ vp_b,
                     const float* __restrict__ tp_w, const float* __restrict__ tp_b,
                     float* __restrict__ Wqv, float* __restrict__ Wkt,
                     float* __restrict__ bqv, float* __restrict__ bkt,
                     unsigned* __restrict__ simMM, unsigned* __restrict__ fiMM) {
  int tx = threadIdx.x, ty = threadIdx.y;
  int bz = blockIdx.z;
  if (bz == 2) {
    if (blockIdx.x || blockIdx.y) return;
    if (ty == 0 && tx < 16) {
      simMM[tx * 2] = 0xFFFFFFFFu; simMM[tx * 2 + 1] = 0u;
      fiMM[tx * 2] = 0xFFFFFFFFu;  fiMM[tx * 2 + 1] = 0u;
    }
    int j = ty * 16 + tx;
    float s1 = 0.f, s2 = 0.f;
    for (int k = 0; k < 256; ++k) {
      s1 += ipw[j * 256 + k] * vp_b[k];
      s2 += ipw[65536 + j * 256 + k] * tp_b[k];
    }
    bqv[j] = s1 + ipb[j];
    bkt[j] = s2 + ipb[256 + j];
    return;
  }
  const float* A = ipw + (bz ? 65536 : 0);
  const float* B = bz ? tp_w : vp_w;
  float* O = bz ? Wkt : Wqv;
  __shared__ float As[16][16], Bs[16][17];
  int row = blockIdx.y * 16 + ty, col = blockIdx.x * 16 + tx;
  float s = 0.f;
  for (int tt = 0; tt < 16; ++tt) {
    As[ty][tx] = A[row * 256 + tt * 16 + tx];
    Bs[ty][tx] = B[(tt * 16 + ty) * 256 + col];
    __syncthreads();
#pragma unroll
    for (int k = 0; k < 16; ++k) s += As[ty][k] * Bs[k][tx];
    __syncthreads();
  }
  O[row * 256 + col] = s;
}

// ---------------- convert W1/W2 to pre-swizzled row-image f16 ----------------
__global__ void k_conv(const float* __restrict__ w1, const float* __restrict__ w2,
                       char* __restrict__ W1g, char* __restrict__ W2g) {
  int i = blockIdx.x * 256 + threadIdx.x;
  if (i < 65536) {
    int o = i >> 8, c = i & 255;
    *(f16*)(W1g + (c >> 6) * 32768 + o * 128 + (((c & 63) << 1) ^ ((o & 7) << 4))) = (f16)w1[i];
  } else if (i < 98304) {
    int i2 = i - 65536;
    int o = i2 >> 8, c = i2 & 255;
    *(f16*)(W2g + (c >> 6) * 16384 + o * 128 + (((c & 63) << 1) ^ ((o & 7) << 4))) = (f16)w2[i2];
  }
}

// ---------------- P2: kp[lb][i] = T[lb]·Wkt[i] + bkt[i] ----------------
__global__ void k_p2(const float* __restrict__ T, const float* __restrict__ Wkt,
                     const float* __restrict__ bkt, float* __restrict__ kp) {
  __shared__ float As[16][16], Ws[16][17];
  int tx = threadIdx.x, ty = threadIdx.y;
  int lb = blockIdx.y * 16 + ty;
  int i = blockIdx.x * 16 + tx;
  float s = 0.f;
  for (int tt = 0; tt < 16; ++tt) {
    As[ty][tx] = T[(size_t)lb * 256 + tt * 16 + tx];
    Ws[ty][tx] = Wkt[(size_t)(blockIdx.x * 16 + ty) * 256 + tt * 16 + tx];
    __syncthreads();
#pragma unroll
    for (int k = 0; k < 16; ++k) s += As[ty][k] * Ws[tx][k];
    __syncthreads();
  }
  kp[(size_t)lb * 256 + i] = s + bkt[i];
}

// ---------------- P3: W2s (pre-swizzled row-image) + sbias ----------------
__global__ void k_p3(const float* __restrict__ kp, const float* __restrict__ Wqv,
                     const float* __restrict__ bqv, char* __restrict__ W2sg,
                     float* __restrict__ sbias) {
  const float SC = 0.17677669529663687f; // 1/sqrt(32)
  int b = blockIdx.z, jt = blockIdx.y, ct = blockIdx.x;
  int ty = threadIdx.y, tx = threadIdx.x;
  int j2 = jt * 16 + ty, c = ct * 16 + tx;
  int h = j2 >> 5, l = j2 & 31;
  const float* kr = kp + (size_t)(l * 16 + b) * 256 + h * 32;
  const float* wq = Wqv + (size_t)h * 32 * 256 + c;
  float s = 0.f;
#pragma unroll
  for (int d = 0; d < 32; ++d) s += kr[d] * wq[(size_t)d * 256];
  *(f16*)(W2sg + (size_t)b * 131072 + (c >> 6) * 32768 + j2 * 128 +
          (((c & 63) << 1) ^ ((j2 & 7) << 4))) = (f16)(s * SC);
  if (ct == 0 && tx == 0) {
    float sb = 0.f;
#pragma unroll
    for (int d = 0; d < 32; ++d) sb += kr[d] * bqv[h * 32 + d];
    sbias[b * 256 + j2] = sb * SC;
  }
}

// ============ k_sc: scores GEMM + softmax + variance + top16 + candidates ============
// 4 waves, 64-n tile. LDS: AT 8K (per-kc X slice, direct f32 staging) + BT 32K (DMA).
// Head-mean via per-wave slices into dead BT (no atomics). 3 blocks/CU.
__global__ void __launch_bounds__(256, 3) k_sc(
    const float* __restrict__ X, const char* __restrict__ W2sg,
    const float* __restrict__ sbias,
    float* __restrict__ cand, float* __restrict__ varpart) {
  __shared__ __align__(16) char smem[40960];  // AT@0 8K, BT@8K 32K (slices alias BT)
  const int b = blockIdx.y;
  const int bx = blockIdx.x;
  const int n0 = bx * 64;
  const int t = threadIdx.x;
  const int w = t >> 6;
  const int lane = t & 63;
  const int ln = lane & 15, kg = lane >> 4;
  char* AT = smem;
  char* BT = smem + 8192;
  const char* Wb = W2sg + (size_t)b * 131072;

  auto issueA = [&](int kt) {
    int row = t >> 2, cq = t & 3;
    const float* Xr = X + ((size_t)(n0 + row) * 16 + b) * 256 + kt * 64 + cq * 16;
    f32x4 a0 = *(const f32x4*)(Xr), a1 = *(const f32x4*)(Xr + 4);
    f32x4 a2 = *(const f32x4*)(Xr + 8), a3 = *(const f32x4*)(Xr + 12);
    half8 h0, h1;
#pragma unroll
    for (int i = 0; i < 4; ++i) {
      h0[i] = (f16)a0[i]; h0[4 + i] = (f16)a1[i];
      h1[i] = (f16)a2[i]; h1[4 + i] = (f16)a3[i];
    }
    unsigned sw = (unsigned)((row & 7) << 4);
    *(half8*)(AT + ((unsigned)(row * 128 + cq * 32) ^ sw)) = h0;
    *(half8*)(AT + ((unsigned)(row * 128 + cq * 32 + 16) ^ sw)) = h1;
  };
  auto issueB = [&](int kt) {
    const char* src = Wb + kt * 32768 + w * 8192 + (lane << 4);
    char* dst = BT + w * 8192;
#pragma unroll
    for (int i = 0; i < 8; ++i) GLOAD16(src + i * 1024, dst + i * 1024);
  };

  f32x4 acc[4][4];
#pragma unroll
  for (int q = 0; q < 4; ++q)
#pragma unroll
    for (int ni = 0; ni < 4; ++ni)
#pragma unroll
      for (int i = 0; i < 4; ++i) acc[q][ni][i] = 0.f;

  issueA(0); issueB(0);
  __syncthreads();
#pragma unroll
  for (int kt = 0; kt < 4; ++kt) {
    half8 av[4][2], bv[4][2];
#pragma unroll
    for (int q = 0; q < 4; ++q) {
      int o = w * 64 + q * 16 + ln;
      unsigned sw = (unsigned)((o & 7) << 4);
#pragma unroll
      for (int mi = 0; mi < 2; ++mi)
        av[q][mi] = *(const half8*)(BT + o * 128 + ((unsigned)(mi * 64 + kg * 16) ^ sw));
    }
#pragma unroll
    for (int ni = 0; ni < 4; ++ni) {
      int n = ni * 16 + ln;
      unsigned sw = (unsigned)((n & 7) << 4);
#pragma unroll
      for (int mi = 0; mi < 2; ++mi)
        bv[ni][mi] = *(const half8*)(AT + n * 128 + ((unsigned)(mi * 64 + kg * 16) ^ sw));
    }
#pragma unroll
    for (int mi = 0; mi < 2; ++mi)
#pragma unroll
      for (int q = 0; q < 4; ++q)
#pragma unroll
        for (int ni = 0; ni < 4; ++ni)
          acc[q][ni] = __builtin_amdgcn_mfma_f32_16x16x32_f16(av[q][mi], bv[ni][mi], acc[q][ni], 0, 0, 0);
    __syncthreads();  // tile reads done
    if (kt < 3) { issueA(kt + 1); issueB(kt + 1); __syncthreads(); }
  }

  // ---- per-head softmax (wave w: heads 2w, 2w+1), local hh-sum, slice to dead BT ----
  {
    f32x4 sb[4];
#pragma unroll
    for (int q = 0; q < 4; ++q)
      sb[q] = *(const f32x4*)(sbias + b * 256 + (w * 4 + q) * 16 + kg * 4);
    float vm[4][2][4];
#pragma unroll
    for (int ni = 0; ni < 4; ++ni)
#pragma unroll
      for (int qq = 0; qq < 2; ++qq)
#pragma unroll
        for (int r = 0; r < 4; ++r) vm[ni][qq][r] = 0.f;
#pragma unroll
    for (int hh = 0; hh < 2; ++hh)
#pragma unroll
      for (int ni = 0; ni < 4; ++ni) {
        float x[2][4];
        float mx = -1e30f;
#pragma unroll
        for (int qq = 0; qq < 2; ++qq)
#pragma unroll
          for (int r = 0; r < 4; ++r) {
            x[qq][r] = acc[hh * 2 + qq][ni][r] + sb[hh * 2 + qq][r];
            mx = fmaxf(mx, x[qq][r]);
          }
        mx = fmaxf(mx, __shfl_xor(mx, 16, 64));
        mx = fmaxf(mx, __shfl_xor(mx, 32, 64));
        float S = 0.f;
#pragma unroll
        for (int qq = 0; qq < 2; ++qq)
#pragma unroll
          for (int r = 0; r < 4; ++r) { x[qq][r] = __expf(x[qq][r] - mx); S += x[qq][r]; }
        S += __shfl_xor(S, 16, 64);
        S += __shfl_xor(S, 32, 64);
        float inv = 0.125f / S;
#pragma unroll
        for (int qq = 0; qq < 2; ++qq)
#pragma unroll
          for (int r = 0; r < 4; ++r) vm[ni][qq][r] += x[qq][r] * inv;
      }
    float* slice = (float*)(smem + 8192) + w * 2048;  // [32 l][64 n]
#pragma unroll
    for (int ni = 0; ni < 4; ++ni)
#pragma unroll
      for (int qq = 0; qq < 2; ++qq)
#pragma unroll
        for (int r = 0; r < 4; ++r)
          slice[(qq * 16 + kg * 4 + r) * 64 + ni * 16 + ln] = vm[ni][qq][r];
  }
  __syncthreads();

  // ---- wave 0: merge slices, variance, sort, candidates ----
  if (w == 0) {
    const float* sl = (const float*)(smem + 8192);
    float v[32];
#pragma unroll
    for (int l = 0; l < 32; ++l)
      v[l] = sl[l * 64 + lane] + sl[2048 + l * 64 + lane] +
             sl[4096 + l * 64 + lane] + sl[6144 + l * 64 + lane];
    float s2 = 0.f;
#pragma unroll
    for (int l = 0; l < 32; ++l) s2 += v[l] * v[l];
    float vr = (s2 - (1.f / 32.f)) * (1.f / 31.f);
#pragma unroll
    for (int m = 1; m < 64; m <<= 1) vr += __shfl_xor(vr, m, 64);
    if (lane == 0) varpart[b * 256 + bx] = vr;
#pragma unroll
    for (int k = 2; k <= 32; k <<= 1) {
#pragma unroll
      for (int j = k >> 1; j > 0; j >>= 1) {
#pragma unroll
        for (int i = 0; i < 32; ++i) {
          int l = i ^ j;
          if (l > i) {
            float a = v[i], c = v[l];
            float hi = fmaxf(a, c), lo = fminf(a, c);
            bool up = ((i & k) == 0);
            v[i] = up ? hi : lo;
            v[l] = up ? lo : hi;
          }
        }
      }
    }
    float m0 = v[0], se = 0.f, te = 0.f;
    float cn[9];
#pragma unroll
    for (int i = 0; i < 16; ++i) {
      float e = __expf(v[i] - m0);
      se += e; te += v[i] * e;
      if (i >= 7) cn[i - 7] = te / se;
    }
#pragma unroll
    for (int i = 0; i < 9; ++i)
      cand[(size_t)i * 262144 + (size_t)b * 16384 + n0 + lane] = cn[i];
  }
}

// ============ k_mlp: MLP1 + LN1 + ReLU + MLP2 + LN2 + ReLU + w3·sigmoid ============
// LDS phase1: AT@0 8K, BT@8K 32K. phase2: H1@0 32K, W2T@32K 16K. 52 KB -> 3/CU.
__global__ void __launch_bounds__(256, 3) k_mlp(
    const float* __restrict__ X,
    const char* __restrict__ W1g, const char* __restrict__ W2g,
    const float* __restrict__ b1, const float* __restrict__ g1, const float* __restrict__ be1,
    const float* __restrict__ b2, const float* __restrict__ g2, const float* __restrict__ be2,
    const float* __restrict__ w3, const float* __restrict__ b3,
    float* __restrict__ fi) {
  __shared__ __align__(16) char smem[49152];
  __shared__ float pSQ[2][64][5];
  __shared__ float pM[64], pR[64];
  const int b = blockIdx.y;
  const int bx = blockIdx.x;
  const int n0 = bx * 64;
  const int t = threadIdx.x;
  const int w = t >> 6;
  const int lane = t & 63;
  const int ln = lane & 15, kg = lane >> 4;
  char* AT = smem;
  char* BT = smem + 8192;
  char* H1 = smem;
  char* W2T = smem + 32768;

  auto issueA = [&](int kt) {
    int row = t >> 2, cq = t & 3;
    const float* Xr = X + ((size_t)(n0 + row) * 16 + b) * 256 + kt * 64 + cq * 16;
    f32x4 a0 = *(const f32x4*)(Xr), a1 = *(const f32x4*)(Xr + 4);
    f32x4 a2 = *(const f32x4*)(Xr + 8), a3 = *(const f32x4*)(Xr + 12);
    half8 h0, h1;
#pragma unroll
    for (int i = 0; i < 4; ++i) {
      h0[i] = (f16)a0[i]; h0[4 + i] = (f16)a1[i];
      h1[i] = (f16)a2[i]; h1[4 + i] = (f16)a3[i];
    }
    unsigned sw = (unsigned)((row & 7) << 4);
    *(half8*)(AT + ((unsigned)(row * 128 + cq * 32) ^ sw)) = h0;
    *(half8*)(AT + ((unsigned)(row * 128 + cq * 32 + 16) ^ sw)) = h1;
  };
  auto issueB1 = [&](int kt) {
    const char* src = W1g + kt * 32768 + w * 8192 + (lane << 4);
    char* dst = BT + w * 8192;
#pragma unroll
    for (int i = 0; i < 8; ++i) GLOAD16(src + i * 1024, dst + i * 1024);
  };
  auto issueW2 = [&](int kt) {
    const char* src = W2g + kt * 16384 + w * 4096 + (lane << 4);
    char* dst = W2T + w * 4096;
    GLOAD16(src, dst);
    GLOAD16(src + 1024, dst + 1024);
    GLOAD16(src + 2048, dst + 2048);
    GLOAD16(src + 3072, dst + 3072);
  };

  // ================= MLP1 GEMM =================
  f32x4 acc[4][4];
#pragma unroll
  for (int q = 0; q < 4; ++q)
#pragma unroll
    for (int ni = 0; ni < 4; ++ni)
#pragma unroll
      for (int i = 0; i < 4; ++i) acc[q][ni][i] = 0.f;

  issueA(0); issueB1(0);
  __syncthreads();
#pragma unroll
  for (int kt = 0; kt < 4; ++kt) {
    half8 av[4][2], bv[4][2];
#pragma unroll
    for (int q = 0; q < 4; ++q) {
      int o = w * 64 + q * 16 + ln;
      unsigned sw = (unsigned)((o & 7) << 4);
#pragma unroll
      for (int mi = 0; mi < 2; ++mi)
        av[q][mi] = *(const half8*)(BT + o * 128 + ((unsigned)(mi * 64 + kg * 16) ^ sw));
    }
#pragma unroll
    for (int ni = 0; ni < 4; ++ni) {
      int n = ni * 16 + ln;
      unsigned sw = (unsigned)((n & 7) << 4);
#pragma unroll
      for (int mi = 0; mi < 2; ++mi)
        bv[ni][mi] = *(const half8*)(AT + n * 128 + ((unsigned)(mi * 64 + kg * 16) ^ sw));
    }
#pragma unroll
    for (int mi = 0; mi < 2; ++mi)
#pragma unroll
      for (int q = 0; q < 4; ++q)
#pragma unroll
        for (int ni = 0; ni < 4; ++ni)
          acc[q][ni] = __builtin_amdgcn_mfma_f32_16x16x32_f16(av[q][mi], bv[ni][mi], acc[q][ni], 0, 0, 0);
    __syncthreads();
    if (kt < 3) { issueA(kt + 1); issueB1(kt + 1); __syncthreads(); }
  }
  // W2 chunk 0 streams into its (now dead) region during the LN1 epilogue
  issueW2(0);

  // ---- b1 + LN1 partials ----
  {
    f32x4 b1v[4];
#pragma unroll
    for (int q = 0; q < 4; ++q)
      b1v[q] = *(const f32x4*)(b1 + (w * 4 + q) * 16 + kg * 4);
#pragma unroll
    for (int ni = 0; ni < 4; ++ni) {
      float s = 0.f, qq = 0.f;
#pragma unroll
      for (int q = 0; q < 4; ++q)
#pragma unroll
        for (int r = 0; r < 4; ++r) {
          float v = acc[q][ni][r] + b1v[q][r];
          acc[q][ni][r] = v;
          s += v; qq += v * v;
        }
      s += __shfl_xor(s, 16, 64); s += __shfl_xor(s, 32, 64);
      qq += __shfl_xor(qq, 16, 64); qq += __shfl_xor(qq, 32, 64);
      if (kg == 0) { int n = ni * 16 + ln; pSQ[0][n][w] = s; pSQ[1][n][w] = qq; }
    }
  }
  __syncthreads();
  if (t < 64) {
    float s = pSQ[0][t][0] + pSQ[0][t][1] + pSQ[0][t][2] + pSQ[0][t][3];
    float q = pSQ[1][t][0] + pSQ[1][t][1] + pSQ[1][t][2] + pSQ[1][t][3];
    float mean = s * (1.f / 256.f);
    float var = q * (1.f / 256.f) - mean * mean;
    pM[t] = mean;
    pR[t] = rsqrtf(var + 1e-5f);
  }
  __syncthreads();

  // ---- LN1 apply + ReLU -> H1 (overwrites AT/BT region) ----
  {
    f32x4 g1v[4], e1v[4];
#pragma unroll
    for (int q = 0; q < 4; ++q) {
      g1v[q] = *(const f32x4*)(g1 + (w * 4 + q) * 16 + kg * 4);
      e1v[q] = *(const f32x4*)(be1 + (w * 4 + q) * 16 + kg * 4);
    }
#pragma unroll
    for (int ni = 0; ni < 4; ++ni) {
      int n = ni * 16 + ln;
      float mean = pM[n], rstd = pR[n];
      unsigned sw = (unsigned)((n & 7) << 4);
#pragma unroll
      for (int q = 0; q < 4; ++q) {
        half4 hv;
#pragma unroll
        for (int r = 0; r < 4; ++r) {
          float y = (acc[q][ni][r] - mean) * rstd * g1v[q][r] + e1v[q][r];
          hv[r] = (f16)fmaxf(y, 0.f);
        }
        *(half4*)(H1 + ((unsigned)(n * 512 + (w * 4 + q) * 32 + kg * 8) ^ sw)) = hv;
      }
    }
  }
  __syncthreads();  // H1 visible, W2T(0) landed (barrier drains vmcnt)

  // ================= MLP2 [128 o2]x[64 n], K=256 =================
  f32x4 acc2[2][4];
#pragma unroll
  for (int oi = 0; oi < 2; ++oi)
#pragma unroll
    for (int ni = 0; ni < 4; ++ni)
#pragma unroll
      for (int i = 0; i < 4; ++i) acc2[oi][ni][i] = 0.f;
#pragma unroll
  for (int kt = 0; kt < 4; ++kt) {
    half8 a2[2][2], bv[4][2];
#pragma unroll
    for (int oi = 0; oi < 2; ++oi) {
      int o2 = w * 32 + oi * 16 + ln;
      unsigned sw = (unsigned)((o2 & 7) << 4);
#pragma unroll
      for (int mi = 0; mi < 2; ++mi)
        a2[oi][mi] = *(const half8*)(W2T + o2 * 128 + ((unsigned)(mi * 64 + kg * 16) ^ sw));
    }
#pragma unroll
    for (int ni = 0; ni < 4; ++ni) {
      int n = ni * 16 + ln;
      unsigned sw = (unsigned)((n & 7) << 4);
#pragma unroll
      for (int mi = 0; mi < 2; ++mi)
        bv[ni][mi] = *(const half8*)(H1 + n * 512 + kt * 128 + ((unsigned)(mi * 64 + kg * 16) ^ sw));
    }
#pragma unroll
    for (int mi = 0; mi < 2; ++mi)
#pragma unroll
      for (int oi = 0; oi < 2; ++oi)
#pragma unroll
        for (int ni = 0; ni < 4; ++ni)
          acc2[oi][ni] = __builtin_amdgcn_mfma_f32_16x16x32_f16(a2[oi][mi], bv[ni][mi], acc2[oi][ni], 0, 0, 0);
    __syncthreads();
    if (kt < 3) { issueW2(kt + 1); __syncthreads(); }
  }

  // ---- LN2 + ReLU + w3 dot + sigmoid -> fi ----
  {
    f32x4 b2v[2], g2v[2], e2v[2], w3v[2];
#pragma unroll
    for (int oi = 0; oi < 2; ++oi) {
      b2v[oi] = *(const f32x4*)(b2 + (w * 2 + oi) * 16 + kg * 4);
      g2v[oi] = *(const f32x4*)(g2 + (w * 2 + oi) * 16 + kg * 4);
      e2v[oi] = *(const f32x4*)(be2 + (w * 2 + oi) * 16 + kg * 4);
      w3v[oi] = *(const f32x4*)(w3 + (w * 2 + oi) * 16 + kg * 4);
    }
#pragma unroll
    for (int ni = 0; ni < 4; ++ni) {
      float s = 0.f, q = 0.f;
#pragma unroll
      for (int oi = 0; oi < 2; ++oi)
#pragma unroll
        for (int r = 0; r < 4; ++r) {
          float v = acc2[oi][ni][r] + b2v[oi][r];
          acc2[oi][ni][r] = v;
          s += v; q += v * v;
        }
      s += __shfl_xor(s, 16, 64); s += __shfl_xor(s, 32, 64);
      q += __shfl_xor(q, 16, 64); q += __shfl_xor(q, 32, 64);
      if (kg == 0) { int n = ni * 16 + ln; pSQ[0][n][w] = s; pSQ[1][n][w] = q; }
    }
    __syncthreads();
    if (t < 64) {
      float s = pSQ[0][t][0] + pSQ[0][t][1] + pSQ[0][t][2] + pSQ[0][t][3];
      float q = pSQ[1][t][0] + pSQ[1][t][1] + pSQ[1][t][2] + pSQ[1][t][3];
      float mean = s * (1.f / 128.f);
      float var = q * (1.f / 128.f) - mean * mean;
      pM[t] = mean;
      pR[t] = rsqrtf(var + 1e-5f);
    }
    __syncthreads();
#pragma unroll
    for (int ni = 0; ni < 4; ++ni) {
      int n = ni * 16 + ln;
      float mean = pM[n], rstd = pR[n];
      float a3 = 0.f;
#pragma unroll
      for (int oi = 0; oi < 2; ++oi)
#pragma unroll
        for (int r = 0; r < 4; ++r) {
          float y = (acc2[oi][ni][r] - mean) * rstd * g2v[oi][r] + e2v[oi][r];
          a3 += fmaxf(y, 0.f) * w3v[oi][r];
        }
      a3 += __shfl_xor(a3, 16, 64);
      a3 += __shfl_xor(a3, 32, 64);
      if (kg == 0) pSQ[0][n][w] = a3;
    }
    __syncthreads();
    if (t < 64) {
      float z = pSQ[0][t][0] + pSQ[0][t][1] + pSQ[0][t][2] + pSQ[0][t][3] + b3[0];
      fi[(size_t)b * 16384 + n0 + t] = sigm(z);
    }
  }
}

// ---------------- G4: ktop + pick sim candidate + min/max reductions ----------------
__global__ void __launch_bounds__(256) k_g4(
    const float* __restrict__ cand, const float* __restrict__ fi,
    const float* __restrict__ varpart, const float* __restrict__ kw,
    float* __restrict__ sim, unsigned* __restrict__ simMM, unsigned* __restrict__ fiMM) {
  __shared__ float red[4][4];
  __shared__ int kS;
  int b = blockIdx.x >> 6;
  if (threadIdx.x < 64) {
    float s = 0.f;
#pragma unroll
    for (int i = 0; i < 4; ++i) s += varpart[b * 256 + threadIdx.x + i * 64];
#pragma unroll
    for (int m = 1; m < 64; m <<= 1) s += __shfl_xor(s, m, 64);
    if (threadIdx.x == 0) {
      float var = s * (1.f / 16384.f);
      float kws = sigm(kw[0]);
      float ratio = fminf(fmaxf(kws * (1.f + var * 0.5f), 0.25f), 0.6f);
      int kb = (int)floorf(32.f * ratio);
      if (kb < 1) kb = 1;
      int kt = kb < 16 ? kb : 16;
      if (kt < 8) kt = 8;
      kS = kt;
    }
  }
  __syncthreads();
  int k = kS;
  int n = (blockIdx.x & 63) * 256 + threadIdx.x;
  size_t idx = (size_t)b * 16384 + n;
  float sv = cand[(size_t)(k - 8) * 262144 + idx];
  sim[idx] = sv;
  float fv = fi[idx];
  float sn = sv, sx = sv, fn = fv, fx = fv;
#pragma unroll
  for (int m = 1; m < 64; m <<= 1) {
    sn = fminf(sn, __shfl_xor(sn, m, 64));
    sx = fmaxf(sx, __shfl_xor(sx, m, 64));
    fn = fminf(fn, __shfl_xor(fn, m, 64));
    fx = fmaxf(fx, __shfl_xor(fx, m, 64));
  }
  int wv = threadIdx.x >> 6;
  if ((threadIdx.x & 63) == 0) { red[0][wv] = sn; red[1][wv] = sx; red[2][wv] = fn; red[3][wv] = fx; }
  __syncthreads();
  if (threadIdx.x == 0) {
    float a = red[0][0], c = red[1][0], d = red[2][0], e = red[3][0];
#pragma unroll
    for (int i = 1; i < 4; ++i) {
      a = fminf(a, red[0][i]); c = fmaxf(c, red[1][i]);
      d = fminf(d, red[2][i]); e = fmaxf(e, red[3][i]);
    }
    atomicMin(&simMM[b * 2 + 0], fmap(a));
    atomicMax(&simMM[b * 2 + 1], fmap(c));
    atomicMin(&fiMM[b * 2 + 0], fmap(d));
    atomicMax(&fiMM[b * 2 + 1], fmap(e));
  }
}

// ---------------- G5: normalize, combine, transpose-write ----------------
__global__ void __launch_bounds__(256) k_g5(
    const float* __restrict__ sim, const float* __restrict__ fi,
    const unsigned* __restrict__ simMM, const unsigned* __restrict__ fiMM,
    const float* __restrict__ ac, const float* __restrict__ af,
    float* __restrict__ out) {
  __shared__ float ls[256][17], lf[256][17];
  __shared__ float sMin[16], sInv[16], fMin[16], fInv[16];
  int t = threadIdx.x;
  int n0 = blockIdx.x * 256;
  if (t < 16) {
    float lo = funmap(simMM[t * 2]), hi = funmap(simMM[t * 2 + 1]);
    float r = hi - lo;
    sMin[t] = lo; sInv[t] = (r > 0.f) ? 1.f / r : 0.f;
    lo = funmap(fiMM[t * 2]); hi = funmap(fiMM[t * 2 + 1]);
    r = hi - lo;
    fMin[t] = lo; fInv[t] = (r > 0.f) ? 1.f / r : 0.f;
  }
#pragma unroll
  for (int i = 0; i < 16; ++i) {
    ls[t][i] = sim[(size_t)i * 16384 + n0 + t];
    lf[t][i] = fi[(size_t)i * 16384 + n0 + t];
  }
  __syncthreads();
  float alpha = 0.5f * (sigm(ac[0]) + sigm(af[0]));
  float o[16];
#pragma unroll
  for (int b = 0; b < 16; ++b) {
    float s = (ls[t][b] - sMin[b]) * sInv[b];
    float f = (lf[t][b] - fMin[b]) * fInv[b];
    o[b] = alpha * s + (1.f - alpha) * f;
  }
  float* op = out + (size_t)(n0 + t) * 16;
#pragma unroll
  for (int i = 0; i < 4; ++i) {
    f32x4 v;
    v[0] = o[i * 4]; v[1] = o[i * 4 + 1]; v[2] = o[i * 4 + 2]; v[3] = o[i * 4 + 3];
    *(f32x4*)(op + i * 4) = v;
  }
}

// ---------------- launcher ----------------
extern "C" void kernel_launch(void* const* d_in, const int* in_sizes, int n_in,
                              void* d_out, int out_size, void* d_ws, size_t ws_size,
                              hipStream_t stream) {
  const float* X    = (const float*)d_in[0];
  const float* T    = (const float*)d_in[1];
  const float* vp_w = (const float*)d_in[2];
  const float* vp_b = (const float*)d_in[3];
  const float* tp_w = (const float*)d_in[4];
  const float* tp_b = (const float*)d_in[5];
  const float* ipw  = (const float*)d_in[6];
  const float* ipb  = (const float*)d_in[7];
  const float* w1   = (const float*)d_in[8];
  const float* b1   = (const float*)d_in[9];
  const float* g1   = (const float*)d_in[10];
  const float* be1  = (const float*)d_in[11];
  const float* w2   = (const float*)d_in[12];
  const float* b2   = (const float*)d_in[13];
  const float* g2   = (const float*)d_in[14];
  const float* be2  = (const float*)d_in[15];
  const float* w3   = (const float*)d_in[16];
  const float* b3   = (const float*)d_in[17];
  const float* kw   = (const float*)d_in[18];
  const float* ac   = (const float*)d_in[19];
  const float* af   = (const float*)d_in[20];
  char* ws = (char*)d_ws;
  float* Wqv = (float*)(ws + WQV_OFF);
  float* Wkt = (float*)(ws + WKT_OFF);
  float* kp = (float*)(ws + KP_OFF);
  char* W2sg = ws + W2S_OFF;
  float* sbias = (float*)(ws + SBIAS_OFF);
  float* bqv = (float*)(ws + BQV_OFF);
  float* bkt = (float*)(ws + BKT_OFF);
  char* W1g = ws + W1H_OFF;
  char* W2g = ws + W2H_OFF;
  float* varpart = (float*)(ws + VARP_OFF);
  unsigned* simMM = (unsigned*)(ws + SMM_OFF);
  unsigned* fiMM = (unsigned*)(ws + FMM_OFF);
  float* cand = (float*)(ws + CAND_OFF);
  float* fi = (float*)(ws + FI_OFF);
  float* sim = (float*)(ws + SIM_OFF);
  float* out = (float*)d_out;

  k_p1<<<dim3(16, 16, 3), dim3(16, 16), 0, stream>>>(ipw, ipb, vp_w, vp_b, tp_w, tp_b,
                                                     Wqv, Wkt, bqv, bkt, simMM, fiMM);
  k_conv<<<384, 256, 0, stream>>>(w1, w2, W1g, W2g);
  k_p2<<<dim3(16, 32), dim3(16, 16), 0, stream>>>(T, Wkt, bkt, kp);
  k_p3<<<dim3(16, 16, 16), dim3(16, 16), 0, stream>>>(kp, Wqv, bqv, W2sg, sbias);
  k_sc<<<dim3(256, 16), 256, 0, stream>>>(X, W2sg, sbias, cand, varpart);
  k_mlp<<<dim3(256, 16), 256, 0, stream>>>(X, W1g, W2g, b1, g1, be1,
                                           b2, g2, be2, w3, b3, fi);
  k_g4<<<1024, 256, 0, stream>>>(cand, fi, varpart, kw, sim, simMM, fiMM);
  k_g5<<<64, 256, 0, stream>>>(sim, fi, simMM, fiMM, ac, af, out);
}

// Round 13
// 250.002 us; speedup vs baseline: 1.3430x; 1.0838x over previous
//
#include <hip/hip_runtime.h>
#include <hip/hip_bf16.h>

typedef _Float16 f16;
typedef _Float16 half8 __attribute__((ext_vector_type(8)));
typedef _Float16 half4 __attribute__((ext_vector_type(4)));
typedef float f32x4 __attribute__((ext_vector_type(4)));

typedef const __attribute__((address_space(1))) void gvoid;
typedef __attribute__((address_space(3))) void lvoid;
#define GLOAD16(src, dst) __builtin_amdgcn_global_load_lds((gvoid*)(src), (lvoid*)(dst), 16, 0, 0)

// ---------------- workspace layout (bytes) ----------------
#define WQV_OFF   0u          // f32 [256][256]  Wq*Vp
#define WKT_OFF   262144u     // f32 [256][256]  Wk*Tp
#define KP_OFF    524288u     // f32 [512][256]  fused k-projection (l*16+b rows)
#define W2S_OFF   1048576u    // row-image W2s: [16 b][4 kc][256 j][128B] (swizzle baked)
#define SBIAS_OFF 3145728u    // f32 [16][256]
#define BQV_OFF   3162112u    // f32 [256]
#define BKT_OFF   3163136u    // f32 [256]
#define W1H_OFF   3164160u    // row-image W1: [4 kc][256 o][128B]
#define W2H_OFF   3295232u    // row-image W2: [4 kc][128 o][128B]
#define VARP_OFF  3360768u    // f32 [16][256]
#define SMM_OFF   3377280u    // u32 [16][2]
#define FMM_OFF   3377408u    // u32 [16][2]
#define CAND_OFF  3377664u    // f32 [9][16][16384]  plane-major candidates
#define FI_OFF    12814848u   // f32 [16][16384]
#define SIM_OFF   13863424u   // f32 [16][16384]

__device__ __forceinline__ float sigm(float x) { return 1.f / (1.f + __expf(-x)); }
__device__ __forceinline__ unsigned fmap(float f) {
  unsigned u = __float_as_uint(f);
  return (u & 0x80000000u) ? ~u : (u | 0x80000000u);
}
__device__ __forceinline__ float funmap(unsigned u) {
  unsigned b = (u & 0x80000000u) ? (u & 0x7FFFFFFFu) : ~u;
  return __uint_as_float(b);
}

// ---------------- P1: Wqv = Wq*Vp, Wkt = Wk*Tp, fused biases (+minmax init) --------
__global__ void k_p1(const float* __restrict__ ipw, const float* __restrict__ ipb,
                     const float* __restrict__ vp_w, const float* __restrict__ vp_b,
                     const float* __restrict__ tp_w, const float* __restrict__ tp_b,
                     float* __restrict__ Wqv, float* __restrict__ Wkt,
                     float* __restrict__ bqv, float* __restrict__ bkt,
                     unsigned* __restrict__ simMM, unsigned* __restrict__ fiMM) {
  int tx = threadIdx.x, ty = threadIdx.y;
  int bz = blockIdx.z;
  if (bz == 2) {
    if (blockIdx.x || blockIdx.y) return;
    if (ty == 0 && tx < 16) {
      simMM[tx * 2] = 0xFFFFFFFFu; simMM[tx * 2 + 1] = 0u;
      fiMM[tx * 2] = 0xFFFFFFFFu;  fiMM[tx * 2 + 1] = 0u;
    }
    int j = ty * 16 + tx;
    float s1 = 0.f, s2 = 0.f;
    for (int k = 0; k < 256; ++k) {
      s1 += ipw[j * 256 + k] * vp_b[k];
      s2 += ipw[65536 + j * 256 + k] * tp_b[k];
    }
    bqv[j] = s1 + ipb[j];
    bkt[j] = s2 + ipb[256 + j];
    return;
  }
  const float* A = ipw + (bz ? 65536 : 0);
  const float* B = bz ? tp_w : vp_w;
  float* O = bz ? Wkt : Wqv;
  __shared__ float As[16][16], Bs[16][17];
  int row = blockIdx.y * 16 + ty, col = blockIdx.x * 16 + tx;
  float s = 0.f;
  for (int tt = 0; tt < 16; ++tt) {
    As[ty][tx] = A[row * 256 + tt * 16 + tx];
    Bs[ty][tx] = B[(tt * 16 + ty) * 256 + col];
    __syncthreads();
#pragma unroll
    for (int k = 0; k < 16; ++k) s += As[ty][k] * Bs[k][tx];
    __syncthreads();
  }
  O[row * 256 + col] = s;
}

// ---------------- convert W1/W2 to pre-swizzled row-image f16 ----------------
__global__ void k_conv(const float* __restrict__ w1, const float* __restrict__ w2,
                       char* __restrict__ W1g, char* __restrict__ W2g) {
  int i = blockIdx.x * 256 + threadIdx.x;
  if (i < 65536) {
    int o = i >> 8, c = i & 255;
    *(f16*)(W1g + (c >> 6) * 32768 + o * 128 + (((c & 63) << 1) ^ ((o & 7) << 4))) = (f16)w1[i];
  } else if (i < 98304) {
    int i2 = i - 65536;
    int o = i2 >> 8, c = i2 & 255;
    *(f16*)(W2g + (c >> 6) * 16384 + o * 128 + (((c & 63) << 1) ^ ((o & 7) << 4))) = (f16)w2[i2];
  }
}

// ---------------- P2: kp[lb][i] = T[lb]·Wkt[i] + bkt[i] ----------------
__global__ void k_p2(const float* __restrict__ T, const float* __restrict__ Wkt,
                     const float* __restrict__ bkt, float* __restrict__ kp) {
  __shared__ float As[16][16], Ws[16][17];
  int tx = threadIdx.x, ty = threadIdx.y;
  int lb = blockIdx.y * 16 + ty;
  int i = blockIdx.x * 16 + tx;
  float s = 0.f;
  for (int tt = 0; tt < 16; ++tt) {
    As[ty][tx] = T[(size_t)lb * 256 + tt * 16 + tx];
    Ws[ty][tx] = Wkt[(size_t)(blockIdx.x * 16 + ty) * 256 + tt * 16 + tx];
    __syncthreads();
#pragma unroll
    for (int k = 0; k < 16; ++k) s += As[ty][k] * Ws[tx][k];
    __syncthreads();
  }
  kp[(size_t)lb * 256 + i] = s + bkt[i];
}

// ---------------- P3: W2s (pre-swizzled row-image) + sbias ----------------
__global__ void k_p3(const float* __restrict__ kp, const float* __restrict__ Wqv,
                     const float* __restrict__ bqv, char* __restrict__ W2sg,
                     float* __restrict__ sbias) {
  const float SC = 0.17677669529663687f; // 1/sqrt(32)
  int b = blockIdx.z, jt = blockIdx.y, ct = blockIdx.x;
  int ty = threadIdx.y, tx = threadIdx.x;
  int j2 = jt * 16 + ty, c = ct * 16 + tx;
  int h = j2 >> 5, l = j2 & 31;
  const float* kr = kp + (size_t)(l * 16 + b) * 256 + h * 32;
  const float* wq = Wqv + (size_t)h * 32 * 256 + c;
  float s = 0.f;
#pragma unroll
  for (int d = 0; d < 32; ++d) s += kr[d] * wq[(size_t)d * 256];
  *(f16*)(W2sg + (size_t)b * 131072 + (c >> 6) * 32768 + j2 * 128 +
          (((c & 63) << 1) ^ ((j2 & 7) << 4))) = (f16)(s * SC);
  if (ct == 0 && tx == 0) {
    float sb = 0.f;
#pragma unroll
    for (int d = 0; d < 32; ++d) sb += kr[d] * bqv[h * 32 + d];
    sbias[b * 256 + j2] = sb * SC;
  }
}

// ============ k_main: blockIdx.z==0 -> scores pipeline ; z==1 -> MLP pipeline ============
// Both block types co-resident (one launch): BW phases of one overlap compute of the other.
// LDS = union: smem 49152 + stats ~3K -> 3 blocks/CU.
__global__ void __launch_bounds__(256, 3) k_main(
    const float* __restrict__ X, const char* __restrict__ W2sg,
    const float* __restrict__ sbias,
    const char* __restrict__ W1g, const char* __restrict__ W2g,
    const float* __restrict__ b1, const float* __restrict__ g1, const float* __restrict__ be1,
    const float* __restrict__ b2, const float* __restrict__ g2, const float* __restrict__ be2,
    const float* __restrict__ w3, const float* __restrict__ b3,
    float* __restrict__ cand, float* __restrict__ varpart, float* __restrict__ fi) {
  __shared__ __align__(16) char smem[49152];
  __shared__ float pSQ[2][64][5];
  __shared__ float pM[64], pR[64];
  const int b = blockIdx.y;
  const int bx = blockIdx.x;
  const int n0 = bx * 64;
  const int t = threadIdx.x;
  const int w = t >> 6;
  const int lane = t & 63;
  const int ln = lane & 15, kg = lane >> 4;
  char* AT = smem;
  char* BT = smem + 8192;

  // X tile staging (shared by both paths): f32 gather -> f16 swizzled LDS rows
  auto issueA = [&](int kt) {
    int row = t >> 2, cq = t & 3;
    const float* Xr = X + ((size_t)(n0 + row) * 16 + b) * 256 + kt * 64 + cq * 16;
    f32x4 a0 = *(const f32x4*)(Xr), a1 = *(const f32x4*)(Xr + 4);
    f32x4 a2 = *(const f32x4*)(Xr + 8), a3 = *(const f32x4*)(Xr + 12);
    half8 h0, h1;
#pragma unroll
    for (int i = 0; i < 4; ++i) {
      h0[i] = (f16)a0[i]; h0[4 + i] = (f16)a1[i];
      h1[i] = (f16)a2[i]; h1[4 + i] = (f16)a3[i];
    }
    unsigned sw = (unsigned)((row & 7) << 4);
    *(half8*)(AT + ((unsigned)(row * 128 + cq * 32) ^ sw)) = h0;
    *(half8*)(AT + ((unsigned)(row * 128 + cq * 32 + 16) ^ sw)) = h1;
  };

  if (blockIdx.z == 0) {
    // ================= scores path =================
    const char* Wb = W2sg + (size_t)b * 131072;
    auto issueB = [&](int kt) {
      const char* src = Wb + kt * 32768 + w * 8192 + (lane << 4);
      char* dst = BT + w * 8192;
#pragma unroll
      for (int i = 0; i < 8; ++i) GLOAD16(src + i * 1024, dst + i * 1024);
    };

    f32x4 acc[4][4];
#pragma unroll
    for (int q = 0; q < 4; ++q)
#pragma unroll
      for (int ni = 0; ni < 4; ++ni)
#pragma unroll
        for (int i = 0; i < 4; ++i) acc[q][ni][i] = 0.f;

    issueA(0); issueB(0);
    __syncthreads();
#pragma unroll
    for (int kt = 0; kt < 4; ++kt) {
      half8 av[4][2], bv[4][2];
#pragma unroll
      for (int q = 0; q < 4; ++q) {
        int o = w * 64 + q * 16 + ln;
        unsigned sw = (unsigned)((o & 7) << 4);
#pragma unroll
        for (int mi = 0; mi < 2; ++mi)
          av[q][mi] = *(const half8*)(BT + o * 128 + ((unsigned)(mi * 64 + kg * 16) ^ sw));
      }
#pragma unroll
      for (int ni = 0; ni < 4; ++ni) {
        int n = ni * 16 + ln;
        unsigned sw = (unsigned)((n & 7) << 4);
#pragma unroll
        for (int mi = 0; mi < 2; ++mi)
          bv[ni][mi] = *(const half8*)(AT + n * 128 + ((unsigned)(mi * 64 + kg * 16) ^ sw));
      }
#pragma unroll
      for (int mi = 0; mi < 2; ++mi)
#pragma unroll
        for (int q = 0; q < 4; ++q)
#pragma unroll
          for (int ni = 0; ni < 4; ++ni)
            acc[q][ni] = __builtin_amdgcn_mfma_f32_16x16x32_f16(av[q][mi], bv[ni][mi], acc[q][ni], 0, 0, 0);
      __syncthreads();
      if (kt < 3) { issueA(kt + 1); issueB(kt + 1); __syncthreads(); }
    }

    // per-head softmax (wave w: heads 2w, 2w+1), slice into dead BT
    {
      f32x4 sb[4];
#pragma unroll
      for (int q = 0; q < 4; ++q)
        sb[q] = *(const f32x4*)(sbias + b * 256 + (w * 4 + q) * 16 + kg * 4);
      float vm[4][2][4];
#pragma unroll
      for (int ni = 0; ni < 4; ++ni)
#pragma unroll
        for (int qq = 0; qq < 2; ++qq)
#pragma unroll
          for (int r = 0; r < 4; ++r) vm[ni][qq][r] = 0.f;
#pragma unroll
      for (int hh = 0; hh < 2; ++hh)
#pragma unroll
        for (int ni = 0; ni < 4; ++ni) {
          float x[2][4];
          float mx = -1e30f;
#pragma unroll
          for (int qq = 0; qq < 2; ++qq)
#pragma unroll
            for (int r = 0; r < 4; ++r) {
              x[qq][r] = acc[hh * 2 + qq][ni][r] + sb[hh * 2 + qq][r];
              mx = fmaxf(mx, x[qq][r]);
            }
          mx = fmaxf(mx, __shfl_xor(mx, 16, 64));
          mx = fmaxf(mx, __shfl_xor(mx, 32, 64));
          float S = 0.f;
#pragma unroll
          for (int qq = 0; qq < 2; ++qq)
#pragma unroll
            for (int r = 0; r < 4; ++r) { x[qq][r] = __expf(x[qq][r] - mx); S += x[qq][r]; }
          S += __shfl_xor(S, 16, 64);
          S += __shfl_xor(S, 32, 64);
          float inv = 0.125f / S;
#pragma unroll
          for (int qq = 0; qq < 2; ++qq)
#pragma unroll
            for (int r = 0; r < 4; ++r) vm[ni][qq][r] += x[qq][r] * inv;
        }
      float* slice = (float*)(smem + 8192) + w * 2048;  // [32 l][64 n]
#pragma unroll
      for (int ni = 0; ni < 4; ++ni)
#pragma unroll
        for (int qq = 0; qq < 2; ++qq)
#pragma unroll
          for (int r = 0; r < 4; ++r)
            slice[(qq * 16 + kg * 4 + r) * 64 + ni * 16 + ln] = vm[ni][qq][r];
    }
    __syncthreads();

    // wave 0: merge slices, variance, sort, candidates
    if (w == 0) {
      const float* sl = (const float*)(smem + 8192);
      float v[32];
#pragma unroll
      for (int l = 0; l < 32; ++l)
        v[l] = sl[l * 64 + lane] + sl[2048 + l * 64 + lane] +
               sl[4096 + l * 64 + lane] + sl[6144 + l * 64 + lane];
      float s2 = 0.f;
#pragma unroll
      for (int l = 0; l < 32; ++l) s2 += v[l] * v[l];
      float vr = (s2 - (1.f / 32.f)) * (1.f / 31.f);
#pragma unroll
      for (int m = 1; m < 64; m <<= 1) vr += __shfl_xor(vr, m, 64);
      if (lane == 0) varpart[b * 256 + bx] = vr;
#pragma unroll
      for (int k = 2; k <= 32; k <<= 1) {
#pragma unroll
        for (int j = k >> 1; j > 0; j >>= 1) {
#pragma unroll
          for (int i = 0; i < 32; ++i) {
            int l = i ^ j;
            if (l > i) {
              float a = v[i], c = v[l];
              float hi = fmaxf(a, c), lo = fminf(a, c);
              bool up = ((i & k) == 0);
              v[i] = up ? hi : lo;
              v[l] = up ? lo : hi;
            }
          }
        }
      }
      float m0 = v[0], se = 0.f, te = 0.f;
      float cn[9];
#pragma unroll
      for (int i = 0; i < 16; ++i) {
        float e = __expf(v[i] - m0);
        se += e; te += v[i] * e;
        if (i >= 7) cn[i - 7] = te / se;
      }
#pragma unroll
      for (int i = 0; i < 9; ++i)
        cand[(size_t)i * 262144 + (size_t)b * 16384 + n0 + lane] = cn[i];
    }
    return;
  }

  // ================= MLP path =================
  char* H1 = smem;
  char* W2T = smem + 32768;
  auto issueB1 = [&](int kt) {
    const char* src = W1g + kt * 32768 + w * 8192 + (lane << 4);
    char* dst = BT + w * 8192;
#pragma unroll
    for (int i = 0; i < 8; ++i) GLOAD16(src + i * 1024, dst + i * 1024);
  };
  auto issueW2 = [&](int kt) {
    const char* src = W2g + kt * 16384 + w * 4096 + (lane << 4);
    char* dst = W2T + w * 4096;
    GLOAD16(src, dst);
    GLOAD16(src + 1024, dst + 1024);
    GLOAD16(src + 2048, dst + 2048);
    GLOAD16(src + 3072, dst + 3072);
  };

  // ---- MLP1 GEMM ----
  f32x4 acc[4][4];
#pragma unroll
  for (int q = 0; q < 4; ++q)
#pragma unroll
    for (int ni = 0; ni < 4; ++ni)
#pragma unroll
      for (int i = 0; i < 4; ++i) acc[q][ni][i] = 0.f;

  issueA(0); issueB1(0);
  __syncthreads();
#pragma unroll
  for (int kt = 0; kt < 4; ++kt) {
    half8 av[4][2], bv[4][2];
#pragma unroll
    for (int q = 0; q < 4; ++q) {
      int o = w * 64 + q * 16 + ln;
      unsigned sw = (unsigned)((o & 7) << 4);
#pragma unroll
      for (int mi = 0; mi < 2; ++mi)
        av[q][mi] = *(const half8*)(BT + o * 128 + ((unsigned)(mi * 64 + kg * 16) ^ sw));
    }
#pragma unroll
    for (int ni = 0; ni < 4; ++ni) {
      int n = ni * 16 + ln;
      unsigned sw = (unsigned)((n & 7) << 4);
#pragma unroll
      for (int mi = 0; mi < 2; ++mi)
        bv[ni][mi] = *(const half8*)(AT + n * 128 + ((unsigned)(mi * 64 + kg * 16) ^ sw));
    }
#pragma unroll
    for (int mi = 0; mi < 2; ++mi)
#pragma unroll
      for (int q = 0; q < 4; ++q)
#pragma unroll
        for (int ni = 0; ni < 4; ++ni)
          acc[q][ni] = __builtin_amdgcn_mfma_f32_16x16x32_f16(av[q][mi], bv[ni][mi], acc[q][ni], 0, 0, 0);
    __syncthreads();
    if (kt < 3) { issueA(kt + 1); issueB1(kt + 1); __syncthreads(); }
  }
  issueW2(0);  // W2 chunk 0 streams during LN1 epilogue

  // ---- b1 + LN1 partials ----
  {
    f32x4 b1v[4];
#pragma unroll
    for (int q = 0; q < 4; ++q)
      b1v[q] = *(const f32x4*)(b1 + (w * 4 + q) * 16 + kg * 4);
#pragma unroll
    for (int ni = 0; ni < 4; ++ni) {
      float s = 0.f, qq = 0.f;
#pragma unroll
      for (int q = 0; q < 4; ++q)
#pragma unroll
        for (int r = 0; r < 4; ++r) {
          float v = acc[q][ni][r] + b1v[q][r];
          acc[q][ni][r] = v;
          s += v; qq += v * v;
        }
      s += __shfl_xor(s, 16, 64); s += __shfl_xor(s, 32, 64);
      qq += __shfl_xor(qq, 16, 64); qq += __shfl_xor(qq, 32, 64);
      if (kg == 0) { int n = ni * 16 + ln; pSQ[0][n][w] = s; pSQ[1][n][w] = qq; }
    }
  }
  __syncthreads();
  if (t < 64) {
    float s = pSQ[0][t][0] + pSQ[0][t][1] + pSQ[0][t][2] + pSQ[0][t][3];
    float q = pSQ[1][t][0] + pSQ[1][t][1] + pSQ[1][t][2] + pSQ[1][t][3];
    float mean = s * (1.f / 256.f);
    float var = q * (1.f / 256.f) - mean * mean;
    pM[t] = mean;
    pR[t] = rsqrtf(var + 1e-5f);
  }
  __syncthreads();

  // ---- LN1 apply + ReLU -> H1 ----
  {
    f32x4 g1v[4], e1v[4];
#pragma unroll
    for (int q = 0; q < 4; ++q) {
      g1v[q] = *(const f32x4*)(g1 + (w * 4 + q) * 16 + kg * 4);
      e1v[q] = *(const f32x4*)(be1 + (w * 4 + q) * 16 + kg * 4);
    }
#pragma unroll
    for (int ni = 0; ni < 4; ++ni) {
      int n = ni * 16 + ln;
      float mean = pM[n], rstd = pR[n];
      unsigned sw = (unsigned)((n & 7) << 4);
#pragma unroll
      for (int q = 0; q < 4; ++q) {
        half4 hv;
#pragma unroll
        for (int r = 0; r < 4; ++r) {
          float y = (acc[q][ni][r] - mean) * rstd * g1v[q][r] + e1v[q][r];
          hv[r] = (f16)fmaxf(y, 0.f);
        }
        *(half4*)(H1 + ((unsigned)(n * 512 + (w * 4 + q) * 32 + kg * 8) ^ sw)) = hv;
      }
    }
  }
  __syncthreads();  // H1 visible, W2T(0) landed

  // ---- MLP2 [128 o2]x[64 n], K=256 ----
  f32x4 acc2[2][4];
#pragma unroll
  for (int oi = 0; oi < 2; ++oi)
#pragma unroll
    for (int ni = 0; ni < 4; ++ni)
#pragma unroll
      for (int i = 0; i < 4; ++i) acc2[oi][ni][i] = 0.f;
#pragma unroll
  for (int kt = 0; kt < 4; ++kt) {
    half8 a2[2][2], bv[4][2];
#pragma unroll
    for (int oi = 0; oi < 2; ++oi) {
      int o2 = w * 32 + oi * 16 + ln;
      unsigned sw = (unsigned)((o2 & 7) << 4);
#pragma unroll
      for (int mi = 0; mi < 2; ++mi)
        a2[oi][mi] = *(const half8*)(W2T + o2 * 128 + ((unsigned)(mi * 64 + kg * 16) ^ sw));
    }
#pragma unroll
    for (int ni = 0; ni < 4; ++ni) {
      int n = ni * 16 + ln;
      unsigned sw = (unsigned)((n & 7) << 4);
#pragma unroll
      for (int mi = 0; mi < 2; ++mi)
        bv[ni][mi] = *(const half8*)(H1 + n * 512 + kt * 128 + ((unsigned)(mi * 64 + kg * 16) ^ sw));
    }
#pragma unroll
    for (int mi = 0; mi < 2; ++mi)
#pragma unroll
      for (int oi = 0; oi < 2; ++oi)
#pragma unroll
        for (int ni = 0; ni < 4; ++ni)
          acc2[oi][ni] = __builtin_amdgcn_mfma_f32_16x16x32_f16(a2[oi][mi], bv[ni][mi], acc2[oi][ni], 0, 0, 0);
    __syncthreads();
    if (kt < 3) { issueW2(kt + 1); __syncthreads(); }
  }

  // ---- LN2 + ReLU + w3 dot + sigmoid -> fi ----
  {
    f32x4 b2v[2], g2v[2], e2v[2], w3v[2];
#pragma unroll
    for (int oi = 0; oi < 2; ++oi) {
      b2v[oi] = *(const f32x4*)(b2 + (w * 2 + oi) * 16 + kg * 4);
      g2v[oi] = *(const f32x4*)(g2 + (w * 2 + oi) * 16 + kg * 4);
      e2v[oi] = *(const f32x4*)(be2 + (w * 2 + oi) * 16 + kg * 4);
      w3v[oi] = *(const f32x4*)(w3 + (w * 2 + oi) * 16 + kg * 4);
    }
#pragma unroll
    for (int ni = 0; ni < 4; ++ni) {
      float s = 0.f, q = 0.f;
#pragma unroll
      for (int oi = 0; oi < 2; ++oi)
#pragma unroll
        for (int r = 0; r < 4; ++r) {
          float v = acc2[oi][ni][r] + b2v[oi][r];
          acc2[oi][ni][r] = v;
          s += v; q += v * v;
        }
      s += __shfl_xor(s, 16, 64); s += __shfl_xor(s, 32, 64);
      q += __shfl_xor(q, 16, 64); q += __shfl_xor(q, 32, 64);
      if (kg == 0) { int n = ni * 16 + ln; pSQ[0][n][w] = s; pSQ[1][n][w] = q; }
    }
    __syncthreads();
    if (t < 64) {
      float s = pSQ[0][t][0] + pSQ[0][t][1] + pSQ[0][t][2] + pSQ[0][t][3];
      float q = pSQ[1][t][0] + pSQ[1][t][1] + pSQ[1][t][2] + pSQ[1][t][3];
      float mean = s * (1.f / 128.f);
      float var = q * (1.f / 128.f) - mean * mean;
      pM[t] = mean;
      pR[t] = rsqrtf(var + 1e-5f);
    }
    __syncthreads();
#pragma unroll
    for (int ni = 0; ni < 4; ++ni) {
      int n = ni * 16 + ln;
      float mean = pM[n], rstd = pR[n];
      float a3 = 0.f;
#pragma unroll
      for (int oi = 0; oi < 2; ++oi)
#pragma unroll
        for (int r = 0; r < 4; ++r) {
          float y = (acc2[oi][ni][r] - mean) * rstd * g2v[oi][r] + e2v[oi][r];
          a3 += fmaxf(y, 0.f) * w3v[oi][r];
        }
      a3 += __shfl_xor(a3, 16, 64);
      a3 += __shfl_xor(a3, 32, 64);
      if (kg == 0) pSQ[0][n][w] = a3;
    }
    __syncthreads();
    if (t < 64) {
      float z = pSQ[0][t][0] + pSQ[0][t][1] + pSQ[0][t][2] + pSQ[0][t][3] + b3[0];
      fi[(size_t)b * 16384 + n0 + t] = sigm(z);
    }
  }
}

// ---------------- G4: ktop + pick sim candidate + min/max reductions ----------------
__global__ void __launch_bounds__(256) k_g4(
    const float* __restrict__ cand, const float* __restrict__ fi,
    const float* __restrict__ varpart, const float* __restrict__ kw,
    float* __restrict__ sim, unsigned* __restrict__ simMM, unsigned* __restrict__ fiMM) {
  __shared__ float red[4][4];
  __shared__ int kS;
  int b = blockIdx.x >> 6;
  if (threadIdx.x < 64) {
    float s = 0.f;
#pragma unroll
    for (int i = 0; i < 4; ++i) s += varpart[b * 256 + threadIdx.x + i * 64];
#pragma unroll
    for (int m = 1; m < 64; m <<= 1) s += __shfl_xor(s, m, 64);
    if (threadIdx.x == 0) {
      float var = s * (1.f / 16384.f);
      float kws = sigm(kw[0]);
      float ratio = fminf(fmaxf(kws * (1.f + var * 0.5f), 0.25f), 0.6f);
      int kb = (int)floorf(32.f * ratio);
      if (kb < 1) kb = 1;
      int kt = kb < 16 ? kb : 16;
      if (kt < 8) kt = 8;
      kS = kt;
    }
  }
  __syncthreads();
  int k = kS;
  int n = (blockIdx.x & 63) * 256 + threadIdx.x;
  size_t idx = (size_t)b * 16384 + n;
  float sv = cand[(size_t)(k - 8) * 262144 + idx];
  sim[idx] = sv;
  float fv = fi[idx];
  float sn = sv, sx = sv, fn = fv, fx = fv;
#pragma unroll
  for (int m = 1; m < 64; m <<= 1) {
    sn = fminf(sn, __shfl_xor(sn, m, 64));
    sx = fmaxf(sx, __shfl_xor(sx, m, 64));
    fn = fminf(fn, __shfl_xor(fn, m, 64));
    fx = fmaxf(fx, __shfl_xor(fx, m, 64));
  }
  int wv = threadIdx.x >> 6;
  if ((threadIdx.x & 63) == 0) { red[0][wv] = sn; red[1][wv] = sx; red[2][wv] = fn; red[3][wv] = fx; }
  __syncthreads();
  if (threadIdx.x == 0) {
    float a = red[0][0], c = red[1][0], d = red[2][0], e = red[3][0];
#pragma unroll
    for (int i = 1; i < 4; ++i) {
      a = fminf(a, red[0][i]); c = fmaxf(c, red[1][i]);
      d = fminf(d, red[2][i]); e = fmaxf(e, red[3][i]);
    }
    atomicMin(&simMM[b * 2 + 0], fmap(a));
    atomicMax(&simMM[b * 2 + 1], fmap(c));
    atomicMin(&fiMM[b * 2 + 0], fmap(d));
    atomicMax(&fiMM[b * 2 + 1], fmap(e));
  }
}

// ---------------- G5: normalize, combine, transpose-write ----------------
__global__ void __launch_bounds__(256) k_g5(
    const float* __restrict__ sim, const float* __restrict__ fi,
    const unsigned* __restrict__ simMM, const unsigned* __restrict__ fiMM,
    const float* __restrict__ ac, const float* __restrict__ af,
    float* __restrict__ out) {
  __shared__ float ls[256][17], lf[256][17];
  __shared__ float sMin[16], sInv[16], fMin[16], fInv[16];
  int t = threadIdx.x;
  int n0 = blockIdx.x * 256;
  if (t < 16) {
    float lo = funmap(simMM[t * 2]), hi = funmap(simMM[t * 2 + 1]);
    float r = hi - lo;
    sMin[t] = lo; sInv[t] = (r > 0.f) ? 1.f / r : 0.f;
    lo = funmap(fiMM[t * 2]); hi = funmap(fiMM[t * 2 + 1]);
    r = hi - lo;
    fMin[t] = lo; fInv[t] = (r > 0.f) ? 1.f / r : 0.f;
  }
#pragma unroll
  for (int i = 0; i < 16; ++i) {
    ls[t][i] = sim[(size_t)i * 16384 + n0 + t];
    lf[t][i] = fi[(size_t)i * 16384 + n0 + t];
  }
  __syncthreads();
  float alpha = 0.5f * (sigm(ac[0]) + sigm(af[0]));
  float o[16];
#pragma unroll
  for (int b = 0; b < 16; ++b) {
    float s = (ls[t][b] - sMin[b]) * sInv[b];
    float f = (lf[t][b] - fMin[b]) * fInv[b];
    o[b] = alpha * s + (1.f - alpha) * f;
  }
  float* op = out + (size_t)(n0 + t) * 16;
#pragma unroll
  for (int i = 0; i < 4; ++i) {
    f32x4 v;
    v[0] = o[i * 4]; v[1] = o[i * 4 + 1]; v[2] = o[i * 4 + 2]; v[3] = o[i * 4 + 3];
    *(f32x4*)(op + i * 4) = v;
  }
}

// ---------------- launcher ----------------
extern "C" void kernel_launch(void* const* d_in, const int* in_sizes, int n_in,
                              void* d_out, int out_size, void* d_ws, size_t ws_size,
                              hipStream_t stream) {
  const float* X    = (const float*)d_in[0];
  const float* T    = (const float*)d_in[1];
  const float* vp_w = (const float*)d_in[2];
  const float* vp_b = (const float*)d_in[3];
  const float* tp_w = (const float*)d_in[4];
  const float* tp_b = (const float*)d_in[5];
  const float* ipw  = (const float*)d_in[6];
  const float* ipb  = (const float*)d_in[7];
  const float* w1   = (const float*)d_in[8];
  const float* b1   = (const float*)d_in[9];
  const float* g1   = (const float*)d_in[10];
  const float* be1  = (const float*)d_in[11];
  const float* w2   = (const float*)d_in[12];
  const float* b2   = (const float*)d_in[13];
  const float* g2   = (const float*)d_in[14];
  const float* be2  = (const float*)d_in[15];
  const float* w3   = (const float*)d_in[16];
  const float* b3   = (const float*)d_in[17];
  const float* kw   = (const float*)d_in[18];
  const float* ac   = (const float*)d_in[19];
  const float* af   = (const float*)d_in[20];
  char* ws = (char*)d_ws;
  float* Wqv = (float*)(ws + WQV_OFF);
  float* Wkt = (float*)(ws + WKT_OFF);
  float* kp = (float*)(ws + KP_OFF);
  char* W2sg = ws + W2S_OFF;
  float* sbias = (float*)(ws + SBIAS_OFF);
  float* bqv = (float*)(ws + BQV_OFF);
  float* bkt = (float*)(ws + BKT_OFF);
  char* W1g = ws + W1H_OFF;
  char* W2g = ws + W2H_OFF;
  float* varpart = (float*)(ws + VARP_OFF);
  unsigned* simMM = (unsigned*)(ws + SMM_OFF);
  unsigned* fiMM = (unsigned*)(ws + FMM_OFF);
  float* cand = (float*)(ws + CAND_OFF);
  float* fi = (float*)(ws + FI_OFF);
  float* sim = (float*)(ws + SIM_OFF);
  float* out = (float*)d_out;

  k_p1<<<dim3(16, 16, 3), dim3(16, 16), 0, stream>>>(ipw, ipb, vp_w, vp_b, tp_w, tp_b,
                                                     Wqv, Wkt, bqv, bkt, simMM, fiMM);
  k_conv<<<384, 256, 0, stream>>>(w1, w2, W1g, W2g);
  k_p2<<<dim3(16, 32), dim3(16, 16), 0, stream>>>(T, Wkt, bkt, kp);
  k_p3<<<dim3(16, 16, 16), dim3(16, 16), 0, stream>>>(kp, Wqv, bqv, W2sg, sbias);
  k_main<<<dim3(256, 16, 2), 256, 0, stream>>>(X, W2sg, sbias, W1g, W2g,
                                               b1, g1, be1, b2, g2, be2, w3, b3,
                                               cand, varpart, fi);
  k_g4<<<1024, 256, 0, stream>>>(cand, fi, varpart, kw, sim, simMM, fiMM);
  k_g5<<<64, 256, 0, stream>>>(sim, fi, simMM, fiMM, ac, af, out);
}